// Round 3
// baseline (583.039 us; speedup 1.0000x reference)
//
#include <hip/hip_runtime.h>

#define FDIM  128
#define NT    16
#define RS    136         // bf16 row stride for sXb/sH/sC
#define FCRS  392         // bf16 row stride for sFC

typedef __attribute__((ext_vector_type(8))) short bf16x8;
typedef __attribute__((ext_vector_type(4))) float f32x4;

__device__ __forceinline__ unsigned short f2bf(float f){
    unsigned u = __builtin_bit_cast(unsigned, f);
    u += 0x7fffu + ((u >> 16) & 1u);          // RNE
    return (unsigned short)(u >> 16);
}
__device__ __forceinline__ float bf2f(unsigned short b){
    unsigned u = ((unsigned)b) << 16;
    return __builtin_bit_cast(float, u);
}
__device__ __forceinline__ float sigf(float x){ return 1.0f/(1.0f+__expf(-x)); }
__device__ __forceinline__ float tanh_(float x){ return 1.0f - 2.0f/(__expf(2.0f*x)+1.0f); }

__global__ void cvt_f32_bf16(const float* __restrict__ src,
                             unsigned short* __restrict__ dst, int n4){
    int i = blockIdx.x * 256 + threadIdx.x;
    if (i < n4){
        float4 v = ((const float4*)src)[i];
        ushort4 b;
        b.x = f2bf(v.x); b.y = f2bf(v.y); b.z = f2bf(v.z); b.w = f2bf(v.w);
        ((ushort4*)dst)[i] = b;
    }
}

__global__ __launch_bounds__(512, 6) void treelstm_mfma(
    const float* __restrict__ X,
    const unsigned short* __restrict__ Wiou,   // [384][128] bf16
    const unsigned short* __restrict__ Uiou,   // [384][384] bf16
    const unsigned short* __restrict__ Wc,     // [128][384] bf16
    const unsigned short* __restrict__ Wf,     // [128][128] bf16
    const unsigned short* __restrict__ Uf,     // [128][128] bf16
    const float* __restrict__ b_iou,
    const float* __restrict__ b_c,
    const float* __restrict__ b_f,
    float* __restrict__ Hout)
{
    // LDS 51712 B -> 3 blocks/CU
    __shared__ char lds[51712];
    unsigned short* sXb = (unsigned short*)lds;            // [64][136] bf16, rows permuted: leaves 0..47, parents 48..63
    unsigned short* sFC = (unsigned short*)lds;            // [16][392] bf16 (alias; X dead after parent tile)
    unsigned short* sH  = (unsigned short*)(lds + 17408);  // [48][136] bf16 leaf h
    unsigned short* sC  = (unsigned short*)(lds + 30464);  // [48][136] bf16 leaf c
    float*          sST = (float*)(lds + 43520);           // [16][128] f32: leaf-tile out / FPRE / parent out (time-shared)

    const int tid  = threadIdx.x;
    const int w    = tid >> 6;
    const int lane = tid & 63;
    const int l15  = lane & 15;
    const int l4   = lane >> 4;
    const int jj   = w * 16 + l15;             // wave's column (0..127 per gate)
    const size_t baseN = (size_t)blockIdx.x * (NT*4);

    // ---- P0: load X, permute rows (leaf li = 3t+pos, parent = 48+t), cvt bf16 ----
    {
        const f32x4* gx = (const f32x4*)(X + baseN * FDIM);
        #pragma unroll
        for (int it = 0; it < 4; ++it){
            int idx  = tid + it * 512;          // 0..2047 float4s
            int nrow = idx >> 5;                // node 0..63
            int c4   = (idx & 31) << 2;
            int t = nrow >> 2, pos = nrow & 3;
            int srow = (pos < 3) ? (t*3 + pos) : (48 + t);
            f32x4 v = __builtin_nontemporal_load(gx + idx);
            ushort4 b;
            b.x = f2bf(v[0]); b.y = f2bf(v[1]); b.z = f2bf(v[2]); b.w = f2bf(v[3]);
            *(ushort4*)&sXb[srow * RS + c4] = b;
        }
    }
    __syncthreads();

    const float bi = b_iou[jj], bo = b_iou[FDIM + jj], bu = b_iou[2*FDIM + jj];

    bf16x8 Bw[3][4];
    #pragma unroll
    for (int g = 0; g < 3; ++g)
        #pragma unroll
        for (int ks = 0; ks < 4; ++ks)
            Bw[g][ks] = *(const bf16x8*)(Wiou + (size_t)(g*FDIM + jj)*FDIM + ks*32 + l4*8);

    // ---- P1: leaf tiles (pure-leaf rows -> uniform epilogue, staged full-line writes) ----
    #pragma unroll
    for (int mt = 0; mt < 3; ++mt){
        f32x4 aI = {0.f,0.f,0.f,0.f}, aO = {0.f,0.f,0.f,0.f}, aU = {0.f,0.f,0.f,0.f};
        #pragma unroll
        for (int ks = 0; ks < 4; ++ks){
            bf16x8 A = *(const bf16x8*)&sXb[(mt*16 + l15)*RS + ks*32 + l4*8];
            aI = __builtin_amdgcn_mfma_f32_16x16x32_bf16(A, Bw[0][ks], aI, 0,0,0);
            aO = __builtin_amdgcn_mfma_f32_16x16x32_bf16(A, Bw[1][ks], aO, 0,0,0);
            aU = __builtin_amdgcn_mfma_f32_16x16x32_bf16(A, Bw[2][ks], aU, 0,0,0);
        }
        #pragma unroll
        for (int r = 0; r < 4; ++r){
            int lr = l4*4 + r;                 // tile-local row
            int li = mt*16 + lr;               // leaf index 0..47
            float cv = sigf(aI[r]+bi) * tanh_(aU[r]+bu);
            float hv = sigf(aO[r]+bo) * tanh_(cv);
            sH[li*RS + jj] = f2bf(hv);
            sC[li*RS + jj] = f2bf(cv);
            sST[lr*FDIM + jj] = hv;
        }
        __syncthreads();
        {   // coalesced copy-out: each wave stores 1 KB contiguous (full lines)
            int row = tid >> 5, c = (tid & 31) << 2;
            int li = mt*16 + row;
            int t  = li / 3;
            int gm = t*4 + (li - 3*t);
            f32x4 hv4 = *(const f32x4*)&sST[row*FDIM + c];
            __builtin_nontemporal_store(hv4, (f32x4*)(Hout + (baseN + gm)*FDIM + c));
        }
        __syncthreads();
    }

    // ---- P1p: parent IOU preacts stay in REGISTERS (+ FPRE from same A-frags) ----
    f32x4 pI = {0.f,0.f,0.f,0.f}, pO = {0.f,0.f,0.f,0.f}, pU = {0.f,0.f,0.f,0.f};
    f32x4 fp = {0.f,0.f,0.f,0.f};
    #pragma unroll
    for (int ks = 0; ks < 4; ++ks){
        bf16x8 A  = *(const bf16x8*)&sXb[(48 + l15)*RS + ks*32 + l4*8];
        bf16x8 Bf = *(const bf16x8*)(Wf + (size_t)jj*FDIM + ks*32 + l4*8);
        pI = __builtin_amdgcn_mfma_f32_16x16x32_bf16(A, Bw[0][ks], pI, 0,0,0);
        pO = __builtin_amdgcn_mfma_f32_16x16x32_bf16(A, Bw[1][ks], pO, 0,0,0);
        pU = __builtin_amdgcn_mfma_f32_16x16x32_bf16(A, Bw[2][ks], pU, 0,0,0);
        fp = __builtin_amdgcn_mfma_f32_16x16x32_bf16(A, Bf, fp, 0,0,0);
    }
    {
        const float bf = b_f[jj];
        #pragma unroll
        for (int r = 0; r < 4; ++r)
            sST[(l4*4 + r)*FDIM + jj] = fp[r] + bf;   // FPRE[tree][col]
    }
    __syncthreads();   // sH/sC/FPRE visible; all sXb reads done -> sFC may overwrite

    // ---- P3: f = sig(FPRE + Uf@h_child); fc = f * c_child -> sFC bf16 ----
    {
        bf16x8 Bu[4];
        #pragma unroll
        for (int ks = 0; ks < 4; ++ks)
            Bu[ks] = *(const bf16x8*)(Uf + (size_t)jj*FDIM + ks*32 + l4*8);
        #pragma unroll
        for (int mt = 0; mt < 3; ++mt){
            f32x4 acc = {0.f,0.f,0.f,0.f};
            #pragma unroll
            for (int ks = 0; ks < 4; ++ks){
                bf16x8 A = *(const bf16x8*)&sH[(mt*16 + l15)*RS + ks*32 + l4*8];
                acc = __builtin_amdgcn_mfma_f32_16x16x32_bf16(A, Bu[ks], acc, 0,0,0);
            }
            #pragma unroll
            for (int r = 0; r < 4; ++r){
                int li = mt*16 + l4*4 + r;
                int t = li / 3, el = li - 3*t;
                float f  = sigf(acc[r] + sST[t*FDIM + jj]);   // own column: same-wave
                float fc = f * bf2f(sC[li*RS + jj]);          // same-lane value
                sFC[t*FCRS + el*FDIM + jj] = f2bf(fc);
            }
        }
    }

    // ---- P2: pIOU += Uiou @ concat(h_children) via MFMA C-in ----
    #pragma unroll
    for (int ks = 0; ks < 12; ++ks){
        bf16x8 A  = *(const bf16x8*)&sH[(3*l15 + (ks>>2))*RS + (ks&3)*32 + l4*8];
        bf16x8 B0 = *(const bf16x8*)(Uiou + (size_t)(0*FDIM + jj)*384 + ks*32 + l4*8);
        bf16x8 B1 = *(const bf16x8*)(Uiou + (size_t)(1*FDIM + jj)*384 + ks*32 + l4*8);
        bf16x8 B2 = *(const bf16x8*)(Uiou + (size_t)(2*FDIM + jj)*384 + ks*32 + l4*8);
        pI = __builtin_amdgcn_mfma_f32_16x16x32_bf16(A, B0, pI, 0,0,0);
        pO = __builtin_amdgcn_mfma_f32_16x16x32_bf16(A, B1, pO, 0,0,0);
        pU = __builtin_amdgcn_mfma_f32_16x16x32_bf16(A, B2, pU, 0,0,0);
    }
    __syncthreads();   // sFC complete block-wide

    // ---- P4: c_p = i*u + Wc@fc + b_c ; h_p staged + coalesced write ----
    {
        f32x4 aC = {0.f,0.f,0.f,0.f};
        #pragma unroll
        for (int ks = 0; ks < 12; ++ks){
            bf16x8 A = *(const bf16x8*)&sFC[l15*FCRS + ks*32 + l4*8];
            bf16x8 B = *(const bf16x8*)(Wc + (size_t)jj*384 + ks*32 + l4*8);
            aC = __builtin_amdgcn_mfma_f32_16x16x32_bf16(A, B, aC, 0,0,0);
        }
        const float bc = b_c[jj];
        #pragma unroll
        for (int r = 0; r < 4; ++r){
            float cp = sigf(pI[r]+bi) * tanh_(pU[r]+bu) + aC[r] + bc;
            float hp = sigf(pO[r]+bo) * tanh_(cp);
            sST[(l4*4 + r)*FDIM + jj] = hp;
        }
    }
    __syncthreads();
    {
        int row = tid >> 5, c = (tid & 31) << 2;
        f32x4 hv4 = *(const f32x4*)&sST[row*FDIM + c];
        __builtin_nontemporal_store(hv4, (f32x4*)(Hout + (baseN + row*4 + 3)*FDIM + c));
    }
}

extern "C" void kernel_launch(void* const* d_in, const int* in_sizes, int n_in,
                              void* d_out, int out_size, void* d_ws, size_t ws_size,
                              hipStream_t stream)
{
    const float* forest = (const float*)d_in[0];
    const float* W_iou  = (const float*)d_in[4];
    const float* b_iou  = (const float*)d_in[5];
    const float* U_iou  = (const float*)d_in[6];
    const float* W_c    = (const float*)d_in[7];
    const float* b_c    = (const float*)d_in[8];
    const float* W_f    = (const float*)d_in[9];
    const float* b_f    = (const float*)d_in[10];
    const float* U_f    = (const float*)d_in[11];
    float* Hout = (float*)d_out;

    unsigned short* wsb = (unsigned short*)d_ws;
    unsigned short* bWiou = wsb;                // 49152 elems
    unsigned short* bUiou = wsb + 49152;        // 147456
    unsigned short* bWc   = wsb + 196608;       // 49152
    unsigned short* bWf   = wsb + 245760;       // 16384
    unsigned short* bUf   = wsb + 262144;       // 16384

    hipLaunchKernelGGL(cvt_f32_bf16, dim3(48),  dim3(256), 0, stream, W_iou, bWiou, 12288);
    hipLaunchKernelGGL(cvt_f32_bf16, dim3(144), dim3(256), 0, stream, U_iou, bUiou, 36864);
    hipLaunchKernelGGL(cvt_f32_bf16, dim3(48),  dim3(256), 0, stream, W_c,   bWc,   12288);
    hipLaunchKernelGGL(cvt_f32_bf16, dim3(16),  dim3(256), 0, stream, W_f,   bWf,   4096);
    hipLaunchKernelGGL(cvt_f32_bf16, dim3(16),  dim3(256), 0, stream, U_f,   bUf,   4096);

    const int trees = in_sizes[0] / (4 * FDIM); // 65536
    const int grid  = trees / NT;               // 4096

    hipLaunchKernelGGL(treelstm_mfma, dim3(grid), dim3(512), 0, stream,
                       forest, bWiou, bUiou, bWc, bWf, bUf, b_iou, b_c, b_f, Hout);
}

// Round 4
// 368.372 us; speedup vs baseline: 1.5827x; 1.5827x over previous
//
#include <hip/hip_runtime.h>

#define FDIM  128
#define NT    16
#define RS    136         // bf16 row stride for sXb/sH/sC
#define FCRS  392         // bf16 row stride for sFC

typedef __attribute__((ext_vector_type(8))) short bf16x8;
typedef __attribute__((ext_vector_type(4))) float f32x4;

__device__ __forceinline__ unsigned short f2bf(float f){
    unsigned u = __builtin_bit_cast(unsigned, f);
    u += 0x7fffu + ((u >> 16) & 1u);          // RNE
    return (unsigned short)(u >> 16);
}
__device__ __forceinline__ float bf2f(unsigned short b){
    unsigned u = ((unsigned)b) << 16;
    return __builtin_bit_cast(float, u);
}
__device__ __forceinline__ float sigf(float x){ return 1.0f/(1.0f+__expf(-x)); }
__device__ __forceinline__ float tanh_(float x){ return 1.0f - 2.0f/(__expf(2.0f*x)+1.0f); }

// ---- fused fp32 -> bf16 conversion of all 5 weight matrices (1 launch) ----
__global__ void cvt_all(const float* __restrict__ W_iou, const float* __restrict__ U_iou,
                        const float* __restrict__ W_c,   const float* __restrict__ W_f,
                        const float* __restrict__ U_f,   unsigned short* __restrict__ dst)
{
    int i = blockIdx.x * 256 + threadIdx.x;      // float4 index, 0..69631 (grid exact)
    const float* src; int base;
    if      (i < 12288){ src = W_iou; base = 0; }
    else if (i < 49152){ src = U_iou; base = 12288; }
    else if (i < 61440){ src = W_c;   base = 49152; }
    else if (i < 65536){ src = W_f;   base = 61440; }
    else               { src = U_f;   base = 65536; }
    float4 v = ((const float4*)src)[i - base];
    ushort4 b;
    b.x = f2bf(v.x); b.y = f2bf(v.y); b.z = f2bf(v.z); b.w = f2bf(v.w);
    ((ushort4*)dst)[i] = b;
}

__global__ __launch_bounds__(512, 4) void treelstm_mfma(
    const float* __restrict__ X,
    const unsigned short* __restrict__ Wiou,   // [384][128] bf16
    const unsigned short* __restrict__ Uiou,   // [384][384] bf16
    const unsigned short* __restrict__ Wc,     // [128][384] bf16
    const unsigned short* __restrict__ Wf,     // [128][128] bf16
    const unsigned short* __restrict__ Uf,     // [128][128] bf16
    const float* __restrict__ b_iou,
    const float* __restrict__ b_c,
    const float* __restrict__ b_f,
    float* __restrict__ Hout)
{
    // LDS 51712 B -> 3 blocks/CU possible (if VGPR <= ~84)
    __shared__ char lds[51712];
    unsigned short* sXb = (unsigned short*)lds;            // [64][136] bf16; rows: leaves 0..47 (3t+pos), parents 48+t
    unsigned short* sFC = (unsigned short*)lds;            // [16][392] bf16 (alias; sXb dead after P1p)
    unsigned short* sH  = (unsigned short*)(lds + 17408);  // [48][136] bf16 leaf h
    unsigned short* sC  = (unsigned short*)(lds + 30464);  // [48][136] bf16 leaf c
    float*          sST = (float*)(lds + 43520);           // [16][128] f32: FPRE, then parent-out staging

    const int tid  = threadIdx.x;
    const int w    = tid >> 6;
    const int lane = tid & 63;
    const int l15  = lane & 15;
    const int l4   = lane >> 4;
    const int jj   = w * 16 + l15;             // wave's output column (0..127 per gate)
    const size_t baseN = (size_t)blockIdx.x * (NT*4);

    // ---- P0: load X, permute rows, convert bf16 ----
    {
        const f32x4* gx = (const f32x4*)(X + baseN * FDIM);
        #pragma unroll
        for (int it = 0; it < 4; ++it){
            int idx  = tid + it * 512;          // 0..2047 float4s
            int nrow = idx >> 5;                // node 0..63
            int c4   = (idx & 31) << 2;
            int t = nrow >> 2, pos = nrow & 3;
            int srow = (pos < 3) ? (t*3 + pos) : (48 + t);
            f32x4 v = gx[idx];
            ushort4 b;
            b.x = f2bf(v[0]); b.y = f2bf(v[1]); b.z = f2bf(v[2]); b.w = f2bf(v[3]);
            *(ushort4*)&sXb[srow * RS + c4] = b;
        }
    }
    __syncthreads();

    const float bi = b_iou[jj], bo = b_iou[FDIM + jj], bu = b_iou[2*FDIM + jj];

    bf16x8 Bw[3][4];
    #pragma unroll
    for (int g = 0; g < 3; ++g)
        #pragma unroll
        for (int ks = 0; ks < 4; ++ks)
            Bw[g][ks] = *(const bf16x8*)(Wiou + (size_t)(g*FDIM + jj)*FDIM + ks*32 + l4*8);

    // ---- P1: leaf IOU tiles; elementwise; direct global stores ----
    #pragma unroll
    for (int mt = 0; mt < 3; ++mt){
        f32x4 aI = {0.f,0.f,0.f,0.f}, aO = {0.f,0.f,0.f,0.f}, aU = {0.f,0.f,0.f,0.f};
        #pragma unroll
        for (int ks = 0; ks < 4; ++ks){
            bf16x8 A = *(const bf16x8*)&sXb[(mt*16 + l15)*RS + ks*32 + l4*8];
            aI = __builtin_amdgcn_mfma_f32_16x16x32_bf16(A, Bw[0][ks], aI, 0,0,0);
            aO = __builtin_amdgcn_mfma_f32_16x16x32_bf16(A, Bw[1][ks], aO, 0,0,0);
            aU = __builtin_amdgcn_mfma_f32_16x16x32_bf16(A, Bw[2][ks], aU, 0,0,0);
        }
        #pragma unroll
        for (int r = 0; r < 4; ++r){
            int li = mt*16 + l4*4 + r;         // leaf 0..47
            int t = li / 3, pos = li - 3*t;
            float cv = sigf(aI[r]+bi) * tanh_(aU[r]+bu);
            float hv = sigf(aO[r]+bo) * tanh_(cv);
            sH[li*RS + jj] = f2bf(hv);
            sC[li*RS + jj] = f2bf(cv);
            Hout[(baseN + t*4 + pos)*FDIM + jj] = hv;
        }
    }

    // ---- P1p: parent IOU preacts -> registers; FPRE from same A-frags ----
    f32x4 pI = {0.f,0.f,0.f,0.f}, pO = {0.f,0.f,0.f,0.f}, pU = {0.f,0.f,0.f,0.f};
    {
        f32x4 fp = {0.f,0.f,0.f,0.f};
        #pragma unroll
        for (int ks = 0; ks < 4; ++ks){
            bf16x8 A  = *(const bf16x8*)&sXb[(48 + l15)*RS + ks*32 + l4*8];
            bf16x8 Bf = *(const bf16x8*)(Wf + (size_t)jj*FDIM + ks*32 + l4*8);
            pI = __builtin_amdgcn_mfma_f32_16x16x32_bf16(A, Bw[0][ks], pI, 0,0,0);
            pO = __builtin_amdgcn_mfma_f32_16x16x32_bf16(A, Bw[1][ks], pO, 0,0,0);
            pU = __builtin_amdgcn_mfma_f32_16x16x32_bf16(A, Bw[2][ks], pU, 0,0,0);
            fp = __builtin_amdgcn_mfma_f32_16x16x32_bf16(A, Bf, fp, 0,0,0);
        }
        const float bf = b_f[jj];
        #pragma unroll
        for (int r = 0; r < 4; ++r)
            sST[(l4*4 + r)*FDIM + jj] = fp[r] + bf;   // FPRE[tree][col]
    }
    __syncthreads();   // sH/sC/FPRE visible; sXb reads done -> sFC may overwrite

    // ---- P3: f = sig(FPRE + Uf@h_child); fc = f * c_child -> sFC bf16 ----
    {
        bf16x8 Bu[4];
        #pragma unroll
        for (int ks = 0; ks < 4; ++ks)
            Bu[ks] = *(const bf16x8*)(Uf + (size_t)jj*FDIM + ks*32 + l4*8);
        #pragma unroll
        for (int mt = 0; mt < 3; ++mt){
            f32x4 acc = {0.f,0.f,0.f,0.f};
            #pragma unroll
            for (int ks = 0; ks < 4; ++ks){
                bf16x8 A = *(const bf16x8*)&sH[(mt*16 + l15)*RS + ks*32 + l4*8];
                acc = __builtin_amdgcn_mfma_f32_16x16x32_bf16(A, Bu[ks], acc, 0,0,0);
            }
            #pragma unroll
            for (int r = 0; r < 4; ++r){
                int li = mt*16 + l4*4 + r;
                int t = li / 3, el = li - 3*t;
                float f  = sigf(acc[r] + sST[t*FDIM + jj]);
                float fc = f * bf2f(sC[li*RS + jj]);
                sFC[t*FCRS + el*FDIM + jj] = f2bf(fc);
            }
        }
    }

    // ---- P2: pIOU += Uiou @ concat(h_children) via MFMA C-in ----
    #pragma unroll
    for (int ks = 0; ks < 12; ++ks){
        bf16x8 A  = *(const bf16x8*)&sH[(3*l15 + (ks>>2))*RS + (ks&3)*32 + l4*8];
        bf16x8 B0 = *(const bf16x8*)(Uiou + (size_t)(0*FDIM + jj)*384 + ks*32 + l4*8);
        bf16x8 B1 = *(const bf16x8*)(Uiou + (size_t)(1*FDIM + jj)*384 + ks*32 + l4*8);
        bf16x8 B2 = *(const bf16x8*)(Uiou + (size_t)(2*FDIM + jj)*384 + ks*32 + l4*8);
        pI = __builtin_amdgcn_mfma_f32_16x16x32_bf16(A, B0, pI, 0,0,0);
        pO = __builtin_amdgcn_mfma_f32_16x16x32_bf16(A, B1, pO, 0,0,0);
        pU = __builtin_amdgcn_mfma_f32_16x16x32_bf16(A, B2, pU, 0,0,0);
    }
    __syncthreads();   // sFC complete block-wide; sST(FPRE) reads done

    // ---- P4: c_p = i*u + Wc@fc + b_c ; h_p staged + coalesced write ----
    {
        f32x4 aC = {0.f,0.f,0.f,0.f};
        #pragma unroll
        for (int ks = 0; ks < 12; ++ks){
            bf16x8 A = *(const bf16x8*)&sFC[l15*FCRS + ks*32 + l4*8];
            bf16x8 B = *(const bf16x8*)(Wc + (size_t)jj*384 + ks*32 + l4*8);
            aC = __builtin_amdgcn_mfma_f32_16x16x32_bf16(A, B, aC, 0,0,0);
        }
        const float bc = b_c[jj];
        #pragma unroll
        for (int r = 0; r < 4; ++r){
            float cp = sigf(pI[r]+bi) * tanh_(pU[r]+bu) + aC[r] + bc;
            float hp = sigf(pO[r]+bo) * tanh_(cp);
            sST[(l4*4 + r)*FDIM + jj] = hp;
        }
    }
    __syncthreads();
    {
        int row = tid >> 5, c = (tid & 31) << 2;
        f32x4 hv4 = *(const f32x4*)&sST[row*FDIM + c];
        *(f32x4*)(Hout + (baseN + row*4 + 3)*FDIM + c) = hv4;
    }
}

extern "C" void kernel_launch(void* const* d_in, const int* in_sizes, int n_in,
                              void* d_out, int out_size, void* d_ws, size_t ws_size,
                              hipStream_t stream)
{
    const float* forest = (const float*)d_in[0];
    const float* W_iou  = (const float*)d_in[4];
    const float* b_iou  = (const float*)d_in[5];
    const float* U_iou  = (const float*)d_in[6];
    const float* W_c    = (const float*)d_in[7];
    const float* b_c    = (const float*)d_in[8];
    const float* W_f    = (const float*)d_in[9];
    const float* b_f    = (const float*)d_in[10];
    const float* U_f    = (const float*)d_in[11];
    float* Hout = (float*)d_out;

    unsigned short* wsb = (unsigned short*)d_ws;
    unsigned short* bWiou = wsb;                // 49152 elems
    unsigned short* bUiou = wsb + 49152;        // 147456
    unsigned short* bWc   = wsb + 196608;       // 49152
    unsigned short* bWf   = wsb + 245760;       // 16384
    unsigned short* bUf   = wsb + 262144;       // 16384

    hipLaunchKernelGGL(cvt_all, dim3(272), dim3(256), 0, stream,
                       W_iou, U_iou, W_c, W_f, U_f, wsb);

    const int trees = in_sizes[0] / (4 * FDIM); // 65536
    const int grid  = trees / NT;               // 4096

    hipLaunchKernelGGL(treelstm_mfma, dim3(grid), dim3(512), 0, stream,
                       forest, bWiou, bUiou, bWc, bWf, bUf, b_iou, b_c, b_f, Hout);
}

// Round 5
// 303.386 us; speedup vs baseline: 1.9218x; 1.2142x over previous
//
#include <hip/hip_runtime.h>

#define FDIM  128
#define NT    16
#define RS    136         // bf16 row stride for sXb/sH/sC
#define FCRS  392         // bf16 row stride for sFC

typedef __attribute__((ext_vector_type(8))) short bf16x8;
typedef __attribute__((ext_vector_type(4))) float f32x4;

__device__ __forceinline__ unsigned short f2bf(float f){
    unsigned u = __builtin_bit_cast(unsigned, f);
    u += 0x7fffu + ((u >> 16) & 1u);          // RNE
    return (unsigned short)(u >> 16);
}
__device__ __forceinline__ float bf2f(unsigned short b){
    unsigned u = ((unsigned)b) << 16;
    return __builtin_bit_cast(float, u);
}
__device__ __forceinline__ float sigf(float x){ return 1.0f/(1.0f+__expf(-x)); }
__device__ __forceinline__ float tanh_(float x){ return 1.0f - 2.0f/(__expf(2.0f*x)+1.0f); }

// ---- fused fp32 -> bf16 conversion of all 5 weight matrices (1 launch) ----
__global__ void cvt_all(const float* __restrict__ W_iou, const float* __restrict__ U_iou,
                        const float* __restrict__ W_c,   const float* __restrict__ W_f,
                        const float* __restrict__ U_f,   unsigned short* __restrict__ dst)
{
    int i = blockIdx.x * 256 + threadIdx.x;      // float4 index, 0..69631
    const float* src; int base;
    if      (i < 12288){ src = W_iou; base = 0; }
    else if (i < 49152){ src = U_iou; base = 12288; }
    else if (i < 61440){ src = W_c;   base = 49152; }
    else if (i < 65536){ src = W_f;   base = 61440; }
    else               { src = U_f;   base = 65536; }
    float4 v = ((const float4*)src)[i - base];
    ushort4 b;
    b.x = f2bf(v.x); b.y = f2bf(v.y); b.z = f2bf(v.z); b.w = f2bf(v.w);
    ((ushort4*)dst)[i] = b;
}

__global__ __launch_bounds__(512, 4) void treelstm_mfma(
    const float* __restrict__ X,
    const unsigned short* __restrict__ Wiou,   // [384][128] bf16
    const unsigned short* __restrict__ Uiou,   // [384][384] bf16
    const unsigned short* __restrict__ Wc,     // [128][384] bf16
    const unsigned short* __restrict__ Wf,     // [128][128] bf16
    const unsigned short* __restrict__ Uf,     // [128][128] bf16
    const float* __restrict__ b_iou,
    const float* __restrict__ b_c,
    const float* __restrict__ b_f,
    float* __restrict__ Hout)
{
    // LDS 76288 B -> 2 blocks/CU
    __shared__ char lds[76288];
    unsigned short* sXb = (unsigned short*)lds;            // [64][136] bf16; leaves rows 0..47 (3t+pos), parents 48+t
    unsigned short* sFC = (unsigned short*)lds;            // [16][392] bf16 (alias low 12.5KB; sXb dead after P1p)
    unsigned short* sH  = (unsigned short*)(lds + 17408);  // [48][136] bf16 leaf h
    unsigned short* sC  = (unsigned short*)(lds + 30464);  // [48][136] bf16 leaf c
    float*          sOUT= (float*)(lds + 43520);           // [64][128] f32 full block output (global node order)
    // FPRE[t][j] aliases sOUT parent rows: sOUT[(4t+3)*128 + j] (dead before P4 writes them)

    const int tid  = threadIdx.x;
    const int w    = tid >> 6;
    const int lane = tid & 63;
    const int l15  = lane & 15;
    const int l4   = lane >> 4;
    const int jj   = w * 16 + l15;             // wave's output column (0..127 per gate)
    const size_t baseN = (size_t)blockIdx.x * (NT*4);

    // ---- issue W-stationary B-fragment loads FIRST (independent of everything) ----
    bf16x8 Bw[3][4];
    #pragma unroll
    for (int g = 0; g < 3; ++g)
        #pragma unroll
        for (int ks = 0; ks < 4; ++ks)
            Bw[g][ks] = *(const bf16x8*)(Wiou + (size_t)(g*FDIM + jj)*FDIM + ks*32 + l4*8);
    bf16x8 Bf[4];
    #pragma unroll
    for (int ks = 0; ks < 4; ++ks)
        Bf[ks] = *(const bf16x8*)(Wf + (size_t)jj*FDIM + ks*32 + l4*8);
    const float bi = b_iou[jj], bo = b_iou[FDIM + jj], bu = b_iou[2*FDIM + jj];
    const float bfv = b_f[jj],  bc = b_c[jj];

    // ---- P0: load X, permute rows, convert bf16 ----
    {
        const f32x4* gx = (const f32x4*)(X + baseN * FDIM);
        #pragma unroll
        for (int it = 0; it < 4; ++it){
            int idx  = tid + it * 512;          // 0..2047 float4s
            int nrow = idx >> 5;                // node 0..63
            int c4   = (idx & 31) << 2;
            int t = nrow >> 2, pos = nrow & 3;
            int srow = (pos < 3) ? (t*3 + pos) : (48 + t);
            f32x4 v = gx[idx];
            ushort4 b;
            b.x = f2bf(v[0]); b.y = f2bf(v[1]); b.z = f2bf(v[2]); b.w = f2bf(v[3]);
            *(ushort4*)&sXb[srow * RS + c4] = b;
        }
    }
    __syncthreads();   // bar1

    // ---- P1: leaf IOU tiles; elementwise; h -> sOUT (f32) + sH/sC (bf16) ----
    #pragma unroll
    for (int mt = 0; mt < 3; ++mt){
        f32x4 aI = {0.f,0.f,0.f,0.f}, aO = {0.f,0.f,0.f,0.f}, aU = {0.f,0.f,0.f,0.f};
        #pragma unroll
        for (int ks = 0; ks < 4; ++ks){
            bf16x8 A = *(const bf16x8*)&sXb[(mt*16 + l15)*RS + ks*32 + l4*8];
            aI = __builtin_amdgcn_mfma_f32_16x16x32_bf16(A, Bw[0][ks], aI, 0,0,0);
            aO = __builtin_amdgcn_mfma_f32_16x16x32_bf16(A, Bw[1][ks], aO, 0,0,0);
            aU = __builtin_amdgcn_mfma_f32_16x16x32_bf16(A, Bw[2][ks], aU, 0,0,0);
        }
        #pragma unroll
        for (int r = 0; r < 4; ++r){
            int li = mt*16 + l4*4 + r;         // leaf 0..47
            int t = li / 3, pos = li - 3*t;
            float cv = sigf(aI[r]+bi) * tanh_(aU[r]+bu);
            float hv = sigf(aO[r]+bo) * tanh_(cv);
            sH[li*RS + jj] = f2bf(hv);
            sC[li*RS + jj] = f2bf(cv);
            sOUT[(t*4 + pos)*FDIM + jj] = hv;
        }
    }

    // ---- P1p: parent IOU preacts -> registers; FPRE -> sOUT parent rows ----
    f32x4 pI = {0.f,0.f,0.f,0.f}, pO = {0.f,0.f,0.f,0.f}, pU = {0.f,0.f,0.f,0.f};
    {
        f32x4 fp = {0.f,0.f,0.f,0.f};
        #pragma unroll
        for (int ks = 0; ks < 4; ++ks){
            bf16x8 A = *(const bf16x8*)&sXb[(48 + l15)*RS + ks*32 + l4*8];
            pI = __builtin_amdgcn_mfma_f32_16x16x32_bf16(A, Bw[0][ks], pI, 0,0,0);
            pO = __builtin_amdgcn_mfma_f32_16x16x32_bf16(A, Bw[1][ks], pO, 0,0,0);
            pU = __builtin_amdgcn_mfma_f32_16x16x32_bf16(A, Bw[2][ks], pU, 0,0,0);
            fp = __builtin_amdgcn_mfma_f32_16x16x32_bf16(A, Bf[ks], fp, 0,0,0);
        }
        #pragma unroll
        for (int r = 0; r < 4; ++r)
            sOUT[(4*(l4*4 + r) + 3)*FDIM + jj] = fp[r] + bfv;   // FPRE[t][jj]
    }

    // issue Uf B-frags before the barrier (hide under barrier wait)
    bf16x8 Bu[4];
    #pragma unroll
    for (int ks = 0; ks < 4; ++ks)
        Bu[ks] = *(const bf16x8*)(Uf + (size_t)jj*FDIM + ks*32 + l4*8);

    __syncthreads();   // bar2: sH/sC/sOUT-leaf/FPRE visible; sXb dead -> sFC writable

    // ---- P3: f = sig(FPRE + Uf@h_child); fc = f * c_child -> sFC bf16 ----
    {
        f32x4 aF0 = {0.f,0.f,0.f,0.f}, aF1 = {0.f,0.f,0.f,0.f}, aF2 = {0.f,0.f,0.f,0.f};
        #pragma unroll
        for (int ks = 0; ks < 4; ++ks){
            bf16x8 A0 = *(const bf16x8*)&sH[( 0 + l15)*RS + ks*32 + l4*8];
            bf16x8 A1 = *(const bf16x8*)&sH[(16 + l15)*RS + ks*32 + l4*8];
            bf16x8 A2 = *(const bf16x8*)&sH[(32 + l15)*RS + ks*32 + l4*8];
            aF0 = __builtin_amdgcn_mfma_f32_16x16x32_bf16(A0, Bu[ks], aF0, 0,0,0);
            aF1 = __builtin_amdgcn_mfma_f32_16x16x32_bf16(A1, Bu[ks], aF1, 0,0,0);
            aF2 = __builtin_amdgcn_mfma_f32_16x16x32_bf16(A2, Bu[ks], aF2, 0,0,0);
        }
        #pragma unroll
        for (int mt = 0; mt < 3; ++mt){
            f32x4 acc = (mt == 0) ? aF0 : (mt == 1) ? aF1 : aF2;
            #pragma unroll
            for (int r = 0; r < 4; ++r){
                int li = mt*16 + l4*4 + r;
                int t = li / 3, el = li - 3*t;
                float f  = sigf(acc[r] + sOUT[(4*t + 3)*FDIM + jj]);  // FPRE
                float fc = f * bf2f(sC[li*RS + jj]);
                sFC[t*FCRS + el*FDIM + jj] = f2bf(fc);
            }
        }
    }

    // ---- P2: pIOU += Uiou @ concat(h_children); 2-deep Uiou prefetch;
    //          Wc B-frags trickle-loaded for P4 ----
    bf16x8 Bc[12];
    {
        bf16x8 Up[2][3];
        #pragma unroll
        for (int p = 0; p < 2; ++p)
            #pragma unroll
            for (int g = 0; g < 3; ++g)
                Up[p][g] = *(const bf16x8*)(Uiou + (size_t)(g*FDIM + jj)*384 + p*32 + l4*8);
        #pragma unroll
        for (int ks = 0; ks < 12; ++ks){
            bf16x8 A  = *(const bf16x8*)&sH[(3*l15 + (ks>>2))*RS + (ks&3)*32 + l4*8];
            bf16x8 b0 = Up[ks&1][0], b1 = Up[ks&1][1], b2 = Up[ks&1][2];
            if (ks < 10){
                #pragma unroll
                for (int g = 0; g < 3; ++g)
                    Up[ks&1][g] = *(const bf16x8*)(Uiou + (size_t)(g*FDIM + jj)*384 + (ks+2)*32 + l4*8);
            }
            Bc[ks] = *(const bf16x8*)(Wc + (size_t)jj*384 + ks*32 + l4*8);
            pI = __builtin_amdgcn_mfma_f32_16x16x32_bf16(A, b0, pI, 0,0,0);
            pO = __builtin_amdgcn_mfma_f32_16x16x32_bf16(A, b1, pO, 0,0,0);
            pU = __builtin_amdgcn_mfma_f32_16x16x32_bf16(A, b2, pU, 0,0,0);
        }
    }
    __syncthreads();   // bar3: sFC complete block-wide; FPRE reads done

    // ---- P4: c_p = i*u + Wc@fc + b_c ; h_p -> sOUT parent rows ----
    {
        f32x4 aC = {0.f,0.f,0.f,0.f};
        #pragma unroll
        for (int ks = 0; ks < 12; ++ks){
            bf16x8 A = *(const bf16x8*)&sFC[l15*FCRS + ks*32 + l4*8];
            aC = __builtin_amdgcn_mfma_f32_16x16x32_bf16(A, Bc[ks], aC, 0,0,0);
        }
        #pragma unroll
        for (int r = 0; r < 4; ++r){
            int t = l4*4 + r;
            float cp = sigf(pI[r]+bi) * tanh_(pU[r]+bu) + aC[r] + bc;
            float hp = sigf(pO[r]+bo) * tanh_(cp);
            sOUT[(t*4 + 3)*FDIM + jj] = hp;
        }
    }
    __syncthreads();   // bar4: sOUT fully populated

    // ---- final dump: 32KB linear, every wave stores full 128B lines ----
    {
        float* go = Hout + baseN * FDIM;
        #pragma unroll
        for (int it = 0; it < 4; ++it){
            int idx = tid + it * 512;           // 0..2047 float4s, linear
            f32x4 v = *(const f32x4*)&sOUT[idx << 2];
            *(f32x4*)(go + (idx << 2)) = v;
        }
    }
}

extern "C" void kernel_launch(void* const* d_in, const int* in_sizes, int n_in,
                              void* d_out, int out_size, void* d_ws, size_t ws_size,
                              hipStream_t stream)
{
    const float* forest = (const float*)d_in[0];
    const float* W_iou  = (const float*)d_in[4];
    const float* b_iou  = (const float*)d_in[5];
    const float* U_iou  = (const float*)d_in[6];
    const float* W_c    = (const float*)d_in[7];
    const float* b_c    = (const float*)d_in[8];
    const float* W_f    = (const float*)d_in[9];
    const float* b_f    = (const float*)d_in[10];
    const float* U_f    = (const float*)d_in[11];
    float* Hout = (float*)d_out;

    unsigned short* wsb = (unsigned short*)d_ws;
    unsigned short* bWiou = wsb;                // 49152 elems
    unsigned short* bUiou = wsb + 49152;        // 147456
    unsigned short* bWc   = wsb + 196608;       // 49152
    unsigned short* bWf   = wsb + 245760;       // 16384
    unsigned short* bUf   = wsb + 262144;       // 16384

    hipLaunchKernelGGL(cvt_all, dim3(272), dim3(256), 0, stream,
                       W_iou, U_iou, W_c, W_f, U_f, wsb);

    const int trees = in_sizes[0] / (4 * FDIM); // 65536
    const int grid  = trees / NT;               // 4096

    hipLaunchKernelGGL(treelstm_mfma, dim3(grid), dim3(512), 0, stream,
                       forest, bWiou, bUiou, bWc, bWf, bUf, b_iou, b_c, b_f, Hout);
}

// Round 6
// 296.027 us; speedup vs baseline: 1.9695x; 1.0249x over previous
//
#include <hip/hip_runtime.h>

#define FDIM  128
#define NT    16
#define RS    136         // bf16 row stride for sXb/sH
#define FCRS  392         // bf16 row stride for sFC

typedef __attribute__((ext_vector_type(8))) short bf16x8;
typedef __attribute__((ext_vector_type(4))) float f32x4;

__device__ __forceinline__ unsigned short f2bf(float f){
    unsigned u = __builtin_bit_cast(unsigned, f);
    u += 0x7fffu + ((u >> 16) & 1u);          // RNE
    return (unsigned short)(u >> 16);
}
__device__ __forceinline__ float sigf(float x){ return 1.0f/(1.0f+__expf(-x)); }
__device__ __forceinline__ float tanh_(float x){ return 1.0f - 2.0f/(__expf(2.0f*x)+1.0f); }

// ---- fused fp32 -> bf16 conversion of all 5 weight matrices (1 launch) ----
__global__ void cvt_all(const float* __restrict__ W_iou, const float* __restrict__ U_iou,
                        const float* __restrict__ W_c,   const float* __restrict__ W_f,
                        const float* __restrict__ U_f,   unsigned short* __restrict__ dst)
{
    int i = blockIdx.x * 256 + threadIdx.x;      // float4 index, 0..69631
    const float* src; int base;
    if      (i < 12288){ src = W_iou; base = 0; }
    else if (i < 49152){ src = U_iou; base = 12288; }
    else if (i < 61440){ src = W_c;   base = 49152; }
    else if (i < 65536){ src = W_f;   base = 61440; }
    else               { src = U_f;   base = 65536; }
    float4 v = ((const float4*)src)[i - base];
    ushort4 b;
    b.x = f2bf(v.x); b.y = f2bf(v.y); b.z = f2bf(v.z); b.w = f2bf(v.w);
    ((ushort4*)dst)[i] = b;
}

__global__ __launch_bounds__(512, 4) void treelstm_mfma(
    const float* __restrict__ X,
    const unsigned short* __restrict__ Wiou,   // [384][128] bf16
    const unsigned short* __restrict__ Uiou,   // [384][384] bf16
    const unsigned short* __restrict__ Wc,     // [128][384] bf16
    const unsigned short* __restrict__ Wf,     // [128][128] bf16
    const unsigned short* __restrict__ Uf,     // [128][128] bf16
    const float* __restrict__ b_iou,
    const float* __restrict__ b_c,
    const float* __restrict__ b_f,
    float* __restrict__ Hout)
{
    // LDS 46848 B -> 3 blocks/CU (needs VGPR <= ~85)
    __shared__ char lds[46848];
    unsigned short* sXb  = (unsigned short*)lds;            // [64][136] bf16; leaves 0..47 (3t+pos), parents 48+t
    unsigned short* sFC  = (unsigned short*)lds;            // [16][392] bf16 (alias; sXb dead after P1p)
    unsigned short* sH   = (unsigned short*)(lds + 17408);  // [48][136] bf16 leaf h
    float*          sFPRE= (float*)(lds + 30464);           // [16][128] f32
    float*          sST  = (float*)(lds + 38656);           // [16][128] f32 output staging (reused 4x)

    const int tid  = threadIdx.x;
    const int w    = tid >> 6;
    const int lane = tid & 63;
    const int l15  = lane & 15;
    const int l4   = lane >> 4;
    const int jj   = w * 16 + l15;             // wave's output column (0..127 per gate)
    const size_t baseN = (size_t)blockIdx.x * (NT*4);

    // ---- W-stationary B-fragments + biases ----
    bf16x8 Bw[3][4];
    #pragma unroll
    for (int g = 0; g < 3; ++g)
        #pragma unroll
        for (int ks = 0; ks < 4; ++ks)
            Bw[g][ks] = *(const bf16x8*)(Wiou + (size_t)(g*FDIM + jj)*FDIM + ks*32 + l4*8);
    bf16x8 Bf[4];
    #pragma unroll
    for (int ks = 0; ks < 4; ++ks)
        Bf[ks] = *(const bf16x8*)(Wf + (size_t)jj*FDIM + ks*32 + l4*8);
    const float bi = b_iou[jj], bo = b_iou[FDIM + jj], bu = b_iou[2*FDIM + jj];
    const float bfv = b_f[jj],  bc = b_c[jj];

    // ---- P0: load X, permute rows, convert bf16 ----
    {
        const f32x4* gx = (const f32x4*)(X + baseN * FDIM);
        #pragma unroll
        for (int it = 0; it < 4; ++it){
            int idx  = tid + it * 512;          // 0..2047 float4s
            int nrow = idx >> 5;                // node 0..63
            int c4   = (idx & 31) << 2;
            int t = nrow >> 2, pos = nrow & 3;
            int srow = (pos < 3) ? (t*3 + pos) : (48 + t);
            f32x4 v = gx[idx];
            ushort4 b;
            b.x = f2bf(v[0]); b.y = f2bf(v[1]); b.z = f2bf(v[2]); b.w = f2bf(v[3]);
            *(ushort4*)&sXb[srow * RS + c4] = b;
        }
    }
    __syncthreads();

    // ---- P1: leaf IOU tiles; c stays in REGISTERS; h -> sH + staged dump ----
    float cvreg[3][4];
    #pragma unroll
    for (int mt = 0; mt < 3; ++mt){
        f32x4 aI = {0.f,0.f,0.f,0.f}, aO = {0.f,0.f,0.f,0.f}, aU = {0.f,0.f,0.f,0.f};
        #pragma unroll
        for (int ks = 0; ks < 4; ++ks){
            bf16x8 A = *(const bf16x8*)&sXb[(mt*16 + l15)*RS + ks*32 + l4*8];
            aI = __builtin_amdgcn_mfma_f32_16x16x32_bf16(A, Bw[0][ks], aI, 0,0,0);
            aO = __builtin_amdgcn_mfma_f32_16x16x32_bf16(A, Bw[1][ks], aO, 0,0,0);
            aU = __builtin_amdgcn_mfma_f32_16x16x32_bf16(A, Bw[2][ks], aU, 0,0,0);
        }
        #pragma unroll
        for (int r = 0; r < 4; ++r){
            int li = mt*16 + l4*4 + r;         // leaf 0..47
            float cv = sigf(aI[r]+bi) * tanh_(aU[r]+bu);
            float hv = sigf(aO[r]+bo) * tanh_(cv);
            cvreg[mt][r] = cv;
            sH[li*RS + jj] = f2bf(hv);
            sST[(l4*4 + r)*FDIM + jj] = hv;
        }
        __syncthreads();   // sST tile complete
        {   // full-line dump: 16 rows x 512B
            int row = tid >> 5, c = (tid & 31) << 2;
            int li = mt*16 + row;
            int t  = li / 3;
            int gm = t*4 + (li - 3*t);
            f32x4 hv4 = *(const f32x4*)&sST[row*FDIM + c];
            *(f32x4*)(Hout + (baseN + gm)*FDIM + c) = hv4;
        }
        __syncthreads();   // sST free for reuse
    }

    // ---- P1p: parent IOU preacts -> registers; FPRE -> sFPRE ----
    f32x4 pI = {0.f,0.f,0.f,0.f}, pO = {0.f,0.f,0.f,0.f}, pU = {0.f,0.f,0.f,0.f};
    {
        f32x4 fp = {0.f,0.f,0.f,0.f};
        #pragma unroll
        for (int ks = 0; ks < 4; ++ks){
            bf16x8 A = *(const bf16x8*)&sXb[(48 + l15)*RS + ks*32 + l4*8];
            pI = __builtin_amdgcn_mfma_f32_16x16x32_bf16(A, Bw[0][ks], pI, 0,0,0);
            pO = __builtin_amdgcn_mfma_f32_16x16x32_bf16(A, Bw[1][ks], pO, 0,0,0);
            pU = __builtin_amdgcn_mfma_f32_16x16x32_bf16(A, Bw[2][ks], pU, 0,0,0);
            fp = __builtin_amdgcn_mfma_f32_16x16x32_bf16(A, Bf[ks], fp, 0,0,0);
        }
        #pragma unroll
        for (int r = 0; r < 4; ++r)
            sFPRE[(l4*4 + r)*FDIM + jj] = fp[r] + bfv;
    }

    // issue Uf B-frags before the barrier
    bf16x8 Bu[4];
    #pragma unroll
    for (int ks = 0; ks < 4; ++ks)
        Bu[ks] = *(const bf16x8*)(Uf + (size_t)jj*FDIM + ks*32 + l4*8);

    __syncthreads();   // sH/sFPRE visible; sXb dead -> sFC writable

    // ---- P3: f = sig(FPRE + Uf@h_child); fc = f * c(reg) -> sFC bf16 ----
    {
        f32x4 aF0 = {0.f,0.f,0.f,0.f}, aF1 = {0.f,0.f,0.f,0.f}, aF2 = {0.f,0.f,0.f,0.f};
        #pragma unroll
        for (int ks = 0; ks < 4; ++ks){
            bf16x8 A0 = *(const bf16x8*)&sH[( 0 + l15)*RS + ks*32 + l4*8];
            bf16x8 A1 = *(const bf16x8*)&sH[(16 + l15)*RS + ks*32 + l4*8];
            bf16x8 A2 = *(const bf16x8*)&sH[(32 + l15)*RS + ks*32 + l4*8];
            aF0 = __builtin_amdgcn_mfma_f32_16x16x32_bf16(A0, Bu[ks], aF0, 0,0,0);
            aF1 = __builtin_amdgcn_mfma_f32_16x16x32_bf16(A1, Bu[ks], aF1, 0,0,0);
            aF2 = __builtin_amdgcn_mfma_f32_16x16x32_bf16(A2, Bu[ks], aF2, 0,0,0);
        }
        #pragma unroll
        for (int mt = 0; mt < 3; ++mt){
            f32x4 acc = (mt == 0) ? aF0 : (mt == 1) ? aF1 : aF2;
            #pragma unroll
            for (int r = 0; r < 4; ++r){
                int li = mt*16 + l4*4 + r;
                int t = li / 3, el = li - 3*t;
                float f  = sigf(acc[r] + sFPRE[t*FDIM + jj]);
                float fc = f * cvreg[mt][r];
                sFC[t*FCRS + el*FDIM + jj] = f2bf(fc);
            }
        }
    }

    // ---- P2: pIOU += Uiou @ concat(h_children); 2-deep Uiou prefetch ----
    {
        bf16x8 Up[2][3];
        #pragma unroll
        for (int p = 0; p < 2; ++p)
            #pragma unroll
            for (int g = 0; g < 3; ++g)
                Up[p][g] = *(const bf16x8*)(Uiou + (size_t)(g*FDIM + jj)*384 + p*32 + l4*8);
        #pragma unroll
        for (int ks = 0; ks < 12; ++ks){
            bf16x8 A  = *(const bf16x8*)&sH[(3*l15 + (ks>>2))*RS + (ks&3)*32 + l4*8];
            bf16x8 b0 = Up[ks&1][0], b1 = Up[ks&1][1], b2 = Up[ks&1][2];
            if (ks < 10){
                #pragma unroll
                for (int g = 0; g < 3; ++g)
                    Up[ks&1][g] = *(const bf16x8*)(Uiou + (size_t)(g*FDIM + jj)*384 + (ks+2)*32 + l4*8);
            }
            pI = __builtin_amdgcn_mfma_f32_16x16x32_bf16(A, b0, pI, 0,0,0);
            pO = __builtin_amdgcn_mfma_f32_16x16x32_bf16(A, b1, pO, 0,0,0);
            pU = __builtin_amdgcn_mfma_f32_16x16x32_bf16(A, b2, pU, 0,0,0);
        }
    }
    __syncthreads();   // sFC complete block-wide; sFPRE reads done

    // ---- P4: c_p = i*u + Wc@fc + b_c ; h_p -> sST -> full-line dump ----
    {
        f32x4 aC = {0.f,0.f,0.f,0.f};
        #pragma unroll
        for (int ks = 0; ks < 12; ++ks){
            bf16x8 A = *(const bf16x8*)&sFC[l15*FCRS + ks*32 + l4*8];
            bf16x8 B = *(const bf16x8*)(Wc + (size_t)jj*384 + ks*32 + l4*8);
            aC = __builtin_amdgcn_mfma_f32_16x16x32_bf16(A, B, aC, 0,0,0);
        }
        #pragma unroll
        for (int r = 0; r < 4; ++r){
            float cp = sigf(pI[r]+bi) * tanh_(pU[r]+bu) + aC[r] + bc;
            float hp = sigf(pO[r]+bo) * tanh_(cp);
            sST[(l4*4 + r)*FDIM + jj] = hp;
        }
    }
    __syncthreads();
    {
        int row = tid >> 5, c = (tid & 31) << 2;
        f32x4 hv4 = *(const f32x4*)&sST[row*FDIM + c];
        *(f32x4*)(Hout + (baseN + row*4 + 3)*FDIM + c) = hv4;
    }
}

extern "C" void kernel_launch(void* const* d_in, const int* in_sizes, int n_in,
                              void* d_out, int out_size, void* d_ws, size_t ws_size,
                              hipStream_t stream)
{
    const float* forest = (const float*)d_in[0];
    const float* W_iou  = (const float*)d_in[4];
    const float* b_iou  = (const float*)d_in[5];
    const float* U_iou  = (const float*)d_in[6];
    const float* W_c    = (const float*)d_in[7];
    const float* b_c    = (const float*)d_in[8];
    const float* W_f    = (const float*)d_in[9];
    const float* b_f    = (const float*)d_in[10];
    const float* U_f    = (const float*)d_in[11];
    float* Hout = (float*)d_out;

    unsigned short* wsb = (unsigned short*)d_ws;
    unsigned short* bWiou = wsb;                // 49152 elems
    unsigned short* bUiou = wsb + 49152;        // 147456
    unsigned short* bWc   = wsb + 196608;       // 49152
    unsigned short* bWf   = wsb + 245760;       // 16384
    unsigned short* bUf   = wsb + 262144;       // 16384

    hipLaunchKernelGGL(cvt_all, dim3(272), dim3(256), 0, stream,
                       W_iou, U_iou, W_c, W_f, U_f, wsb);

    const int trees = in_sizes[0] / (4 * FDIM); // 65536
    const int grid  = trees / NT;               // 4096

    hipLaunchKernelGGL(treelstm_mfma, dim3(grid), dim3(512), 0, stream,
                       forest, bWiou, bUiou, bWc, bWf, bUf, b_iou, b_c, b_f, Hout);
}

// Round 7
// 289.632 us; speedup vs baseline: 2.0130x; 1.0221x over previous
//
#include <hip/hip_runtime.h>

#define FDIM  128
#define NT    16
#define RS    136         // bf16 row stride for sXb/sH
#define FCRS  392         // bf16 row stride for sFC

typedef __attribute__((ext_vector_type(8))) short bf16x8;
typedef __attribute__((ext_vector_type(4))) float f32x4;

__device__ __forceinline__ unsigned short f2bf(float f){
    unsigned u = __builtin_bit_cast(unsigned, f);
    u += 0x7fffu + ((u >> 16) & 1u);          // RNE
    return (unsigned short)(u >> 16);
}
__device__ __forceinline__ float bf2f(unsigned short b){
    unsigned u = ((unsigned)b) << 16;
    return __builtin_bit_cast(float, u);
}
__device__ __forceinline__ float sigf(float x){ return 1.0f/(1.0f+__expf(-x)); }
__device__ __forceinline__ float tanh_(float x){ return 1.0f - 2.0f/(__expf(2.0f*x)+1.0f); }

// ---- fused fp32 -> bf16 conversion of all 5 weight matrices (1 launch) ----
__global__ void cvt_all(const float* __restrict__ W_iou, const float* __restrict__ U_iou,
                        const float* __restrict__ W_c,   const float* __restrict__ W_f,
                        const float* __restrict__ U_f,   unsigned short* __restrict__ dst)
{
    int i = blockIdx.x * 256 + threadIdx.x;      // float4 index, 0..69631
    const float* src; int base;
    if      (i < 12288){ src = W_iou; base = 0; }
    else if (i < 49152){ src = U_iou; base = 12288; }
    else if (i < 61440){ src = W_c;   base = 49152; }
    else if (i < 65536){ src = W_f;   base = 61440; }
    else               { src = U_f;   base = 65536; }
    float4 v = ((const float4*)src)[i - base];
    ushort4 b;
    b.x = f2bf(v.x); b.y = f2bf(v.y); b.z = f2bf(v.z); b.w = f2bf(v.w);
    ((ushort4*)dst)[i] = b;
}

__global__ __launch_bounds__(512, 4) void treelstm_mfma(
    const float* __restrict__ X,
    const unsigned short* __restrict__ Wiou,   // [384][128] bf16
    const unsigned short* __restrict__ Uiou,   // [384][384] bf16
    const unsigned short* __restrict__ Wc,     // [128][384] bf16
    const unsigned short* __restrict__ Wf,     // [128][128] bf16
    const unsigned short* __restrict__ Uf,     // [128][128] bf16
    const float* __restrict__ b_iou,
    const float* __restrict__ b_c,
    const float* __restrict__ b_f,
    float* __restrict__ Hout)
{
    // LDS 43008 B
    __shared__ char lds[43008];
    unsigned short* sXb  = (unsigned short*)lds;            // [64][136]; leaves rows 0..47 (3t+pos), parents 48+t
    unsigned short* sFC  = (unsigned short*)lds;            // [16][392] (alias; sXb dead after P1p)
    unsigned short* sH   = (unsigned short*)(lds + 17408);  // [64][136]; rows 0..47 leaf h, 48..63 parent h
    float*          sFPRE= (float*)(lds + 34816);           // [16][128] f32

    const int tid  = threadIdx.x;
    const int w    = tid >> 6;
    const int lane = tid & 63;
    const int l15  = lane & 15;
    const int l4   = lane >> 4;
    const int jj   = w * 16 + l15;             // wave's output column (0..127 per gate)
    const size_t baseN = (size_t)blockIdx.x * (NT*4);

    // ---- W-stationary B-fragments + biases ----
    bf16x8 Bw[3][4];
    #pragma unroll
    for (int g = 0; g < 3; ++g)
        #pragma unroll
        for (int ks = 0; ks < 4; ++ks)
            Bw[g][ks] = *(const bf16x8*)(Wiou + (size_t)(g*FDIM + jj)*FDIM + ks*32 + l4*8);
    bf16x8 Bf[4];
    #pragma unroll
    for (int ks = 0; ks < 4; ++ks)
        Bf[ks] = *(const bf16x8*)(Wf + (size_t)jj*FDIM + ks*32 + l4*8);
    const float bi = b_iou[jj], bo = b_iou[FDIM + jj], bu = b_iou[2*FDIM + jj];
    const float bfv = b_f[jj],  bc = b_c[jj];

    // ---- P0: load X, permute rows, convert bf16 ----
    {
        const f32x4* gx = (const f32x4*)(X + baseN * FDIM);
        #pragma unroll
        for (int it = 0; it < 4; ++it){
            int idx  = tid + it * 512;          // 0..2047 float4s
            int nrow = idx >> 5;                // node 0..63
            int c4   = (idx & 31) << 2;
            int t = nrow >> 2, pos = nrow & 3;
            int srow = (pos < 3) ? (t*3 + pos) : (48 + t);
            f32x4 v = gx[idx];
            ushort4 b;
            b.x = f2bf(v[0]); b.y = f2bf(v[1]); b.z = f2bf(v[2]); b.w = f2bf(v[3]);
            *(ushort4*)&sXb[srow * RS + c4] = b;
        }
    }
    __syncthreads();                           // B1

    // ---- P1: leaf IOU tiles; c -> registers, h -> sH (bf16) only ----
    float cvreg[3][4];
    #pragma unroll
    for (int mt = 0; mt < 3; ++mt){
        f32x4 aI = {0.f,0.f,0.f,0.f}, aO = {0.f,0.f,0.f,0.f}, aU = {0.f,0.f,0.f,0.f};
        #pragma unroll
        for (int ks = 0; ks < 4; ++ks){
            bf16x8 A = *(const bf16x8*)&sXb[(mt*16 + l15)*RS + ks*32 + l4*8];
            aI = __builtin_amdgcn_mfma_f32_16x16x32_bf16(A, Bw[0][ks], aI, 0,0,0);
            aO = __builtin_amdgcn_mfma_f32_16x16x32_bf16(A, Bw[1][ks], aO, 0,0,0);
            aU = __builtin_amdgcn_mfma_f32_16x16x32_bf16(A, Bw[2][ks], aU, 0,0,0);
        }
        #pragma unroll
        for (int r = 0; r < 4; ++r){
            int li = mt*16 + l4*4 + r;         // leaf 0..47
            float cv = sigf(aI[r]+bi) * tanh_(aU[r]+bu);
            float hv = sigf(aO[r]+bo) * tanh_(cv);
            cvreg[mt][r] = cv;
            sH[li*RS + jj] = f2bf(hv);
        }
    }

    // ---- P1p: parent IOU preacts -> registers; FPRE -> sFPRE ----
    f32x4 pI = {0.f,0.f,0.f,0.f}, pO = {0.f,0.f,0.f,0.f}, pU = {0.f,0.f,0.f,0.f};
    {
        f32x4 fp = {0.f,0.f,0.f,0.f};
        #pragma unroll
        for (int ks = 0; ks < 4; ++ks){
            bf16x8 A = *(const bf16x8*)&sXb[(48 + l15)*RS + ks*32 + l4*8];
            pI = __builtin_amdgcn_mfma_f32_16x16x32_bf16(A, Bw[0][ks], pI, 0,0,0);
            pO = __builtin_amdgcn_mfma_f32_16x16x32_bf16(A, Bw[1][ks], pO, 0,0,0);
            pU = __builtin_amdgcn_mfma_f32_16x16x32_bf16(A, Bw[2][ks], pU, 0,0,0);
            fp = __builtin_amdgcn_mfma_f32_16x16x32_bf16(A, Bf[ks], fp, 0,0,0);
        }
        #pragma unroll
        for (int r = 0; r < 4; ++r)
            sFPRE[(l4*4 + r)*FDIM + jj] = fp[r] + bfv;
    }

    // issue Uf B-frags before the barrier (latency hidden under barrier wait)
    bf16x8 Bu[4];
    #pragma unroll
    for (int ks = 0; ks < 4; ++ks)
        Bu[ks] = *(const bf16x8*)(Uf + (size_t)jj*FDIM + ks*32 + l4*8);

    __syncthreads();                           // B2: sH/sFPRE visible; sXb dead -> sFC writable

    // ---- P3: f = sig(FPRE + Uf@h_child); fc = f * c(reg) -> sFC bf16 ----
    {
        f32x4 aF0 = {0.f,0.f,0.f,0.f}, aF1 = {0.f,0.f,0.f,0.f}, aF2 = {0.f,0.f,0.f,0.f};
        #pragma unroll
        for (int ks = 0; ks < 4; ++ks){
            bf16x8 A0 = *(const bf16x8*)&sH[( 0 + l15)*RS + ks*32 + l4*8];
            bf16x8 A1 = *(const bf16x8*)&sH[(16 + l15)*RS + ks*32 + l4*8];
            bf16x8 A2 = *(const bf16x8*)&sH[(32 + l15)*RS + ks*32 + l4*8];
            aF0 = __builtin_amdgcn_mfma_f32_16x16x32_bf16(A0, Bu[ks], aF0, 0,0,0);
            aF1 = __builtin_amdgcn_mfma_f32_16x16x32_bf16(A1, Bu[ks], aF1, 0,0,0);
            aF2 = __builtin_amdgcn_mfma_f32_16x16x32_bf16(A2, Bu[ks], aF2, 0,0,0);
        }
        #pragma unroll
        for (int mt = 0; mt < 3; ++mt){
            f32x4 acc = (mt == 0) ? aF0 : (mt == 1) ? aF1 : aF2;
            #pragma unroll
            for (int r = 0; r < 4; ++r){
                int li = mt*16 + l4*4 + r;
                int t = li / 3, el = li - 3*t;
                float f  = sigf(acc[r] + sFPRE[t*FDIM + jj]);
                float fc = f * cvreg[mt][r];
                sFC[t*FCRS + el*FDIM + jj] = f2bf(fc);
            }
        }
    }

    // ---- P2: pIOU += Uiou @ concat(h_children); 4-deep Uiou prefetch ----
    {
        bf16x8 Up[4][3];
        #pragma unroll
        for (int p = 0; p < 4; ++p)
            #pragma unroll
            for (int g = 0; g < 3; ++g)
                Up[p][g] = *(const bf16x8*)(Uiou + (size_t)(g*FDIM + jj)*384 + p*32 + l4*8);
        #pragma unroll
        for (int ks = 0; ks < 12; ++ks){
            bf16x8 A  = *(const bf16x8*)&sH[(3*l15 + (ks>>2))*RS + (ks&3)*32 + l4*8];
            bf16x8 b0 = Up[ks&3][0], b1 = Up[ks&3][1], b2 = Up[ks&3][2];
            if (ks < 8){
                #pragma unroll
                for (int g = 0; g < 3; ++g)
                    Up[ks&3][g] = *(const bf16x8*)(Uiou + (size_t)(g*FDIM + jj)*384 + (ks+4)*32 + l4*8);
            }
            pI = __builtin_amdgcn_mfma_f32_16x16x32_bf16(A, b0, pI, 0,0,0);
            pO = __builtin_amdgcn_mfma_f32_16x16x32_bf16(A, b1, pO, 0,0,0);
            pU = __builtin_amdgcn_mfma_f32_16x16x32_bf16(A, b2, pU, 0,0,0);
        }
    }
    __syncthreads();                           // B3: sFC complete block-wide

    // ---- P4: c_p = i*u + Wc@fc + b_c ; h_p (bf16) -> sH rows 48..63 ----
    {
        f32x4 aC = {0.f,0.f,0.f,0.f};
        #pragma unroll
        for (int ks = 0; ks < 12; ++ks){
            bf16x8 A = *(const bf16x8*)&sFC[l15*FCRS + ks*32 + l4*8];
            bf16x8 B = *(const bf16x8*)(Wc + (size_t)jj*384 + ks*32 + l4*8);
            aC = __builtin_amdgcn_mfma_f32_16x16x32_bf16(A, B, aC, 0,0,0);
        }
        #pragma unroll
        for (int r = 0; r < 4; ++r){
            int t = l4*4 + r;
            float cp = sigf(pI[r]+bi) * tanh_(pU[r]+bu) + aC[r] + bc;
            float hp = sigf(pO[r]+bo) * tanh_(cp);
            sH[(48 + t)*RS + jj] = f2bf(hp);
        }
    }
    __syncthreads();                           // B4: sH fully populated

    // ---- final dump: bf16 -> f32 convert, full-line coalesced stores ----
    {
        float* go = Hout + baseN * FDIM;
        #pragma unroll
        for (int it = 0; it < 4; ++it){
            int idx  = tid + it * 512;          // 0..2047 8B-chunks
            int nrow = idx >> 5;                // node 0..63 (global order)
            int c4   = (idx & 31) << 2;
            int t = nrow >> 2, pos = nrow & 3;
            int srow = (pos < 3) ? (t*3 + pos) : (48 + t);
            ushort4 hb = *(const ushort4*)&sH[srow * RS + c4];
            f32x4 v;
            v[0] = bf2f(hb.x); v[1] = bf2f(hb.y); v[2] = bf2f(hb.z); v[3] = bf2f(hb.w);
            *(f32x4*)(go + nrow*FDIM + c4) = v;
        }
    }
}

extern "C" void kernel_launch(void* const* d_in, const int* in_sizes, int n_in,
                              void* d_out, int out_size, void* d_ws, size_t ws_size,
                              hipStream_t stream)
{
    const float* forest = (const float*)d_in[0];
    const float* W_iou  = (const float*)d_in[4];
    const float* b_iou  = (const float*)d_in[5];
    const float* U_iou  = (const float*)d_in[6];
    const float* W_c    = (const float*)d_in[7];
    const float* b_c    = (const float*)d_in[8];
    const float* W_f    = (const float*)d_in[9];
    const float* b_f    = (const float*)d_in[10];
    const float* U_f    = (const float*)d_in[11];
    float* Hout = (float*)d_out;

    unsigned short* wsb = (unsigned short*)d_ws;
    unsigned short* bWiou = wsb;                // 49152 elems
    unsigned short* bUiou = wsb + 49152;        // 147456
    unsigned short* bWc   = wsb + 196608;       // 49152
    unsigned short* bWf   = wsb + 245760;       // 16384
    unsigned short* bUf   = wsb + 262144;       // 16384

    hipLaunchKernelGGL(cvt_all, dim3(272), dim3(256), 0, stream,
                       W_iou, U_iou, W_c, W_f, U_f, wsb);

    const int trees = in_sizes[0] / (4 * FDIM); // 65536
    const int grid  = trees / NT;               // 4096

    hipLaunchKernelGGL(treelstm_mfma, dim3(grid), dim3(512), 0, stream,
                       forest, bWiou, bUiou, bWc, bWf, bUf, b_iou, b_c, b_f, Hout);
}

// Round 8
// 266.834 us; speedup vs baseline: 2.1850x; 1.0854x over previous
//
#include <hip/hip_runtime.h>

#define FDIM  128
#define NTT   32          // trees per block
#define RS    136         // bf16 row stride for sXb/sH/sAux
#define FCRS  392         // bf16 row stride for sFC

typedef __attribute__((ext_vector_type(8))) short bf16x8;
typedef __attribute__((ext_vector_type(4))) float f32x4;

__device__ __forceinline__ unsigned short f2bf(float f){
    unsigned u = __builtin_bit_cast(unsigned, f);
    u += 0x7fffu + ((u >> 16) & 1u);          // RNE
    return (unsigned short)(u >> 16);
}
__device__ __forceinline__ float bf2f(unsigned short b){
    unsigned u = ((unsigned)b) << 16;
    return __builtin_bit_cast(float, u);
}
__device__ __forceinline__ float sigf(float x){ return 1.0f/(1.0f+__expf(-x)); }
__device__ __forceinline__ float tanh_(float x){ return 1.0f - 2.0f/(__expf(2.0f*x)+1.0f); }

// ---- fused fp32 -> bf16 conversion of all 5 weight matrices (1 launch) ----
__global__ void cvt_all(const float* __restrict__ W_iou, const float* __restrict__ U_iou,
                        const float* __restrict__ W_c,   const float* __restrict__ W_f,
                        const float* __restrict__ U_f,   unsigned short* __restrict__ dst)
{
    int i = blockIdx.x * 256 + threadIdx.x;      // float4 index, 0..69631
    const float* src; int base;
    if      (i < 12288){ src = W_iou; base = 0; }
    else if (i < 49152){ src = U_iou; base = 12288; }
    else if (i < 61440){ src = W_c;   base = 49152; }
    else if (i < 65536){ src = W_f;   base = 61440; }
    else               { src = U_f;   base = 65536; }
    float4 v = ((const float4*)src)[i - base];
    ushort4 b;
    b.x = f2bf(v.x); b.y = f2bf(v.y); b.z = f2bf(v.z); b.w = f2bf(v.w);
    ((ushort4*)dst)[i] = b;
}

__global__ __launch_bounds__(512, 4) void treelstm_mfma(
    const float* __restrict__ X,
    const unsigned short* __restrict__ Wiou,   // [384][128] bf16
    const unsigned short* __restrict__ Uiou,   // [384][384] bf16
    const unsigned short* __restrict__ Wc,     // [128][384] bf16
    const unsigned short* __restrict__ Wf,     // [128][128] bf16
    const unsigned short* __restrict__ Uf,     // [128][128] bf16
    const float* __restrict__ b_iou,
    const float* __restrict__ b_c,
    const float* __restrict__ b_f,
    float* __restrict__ Hout)
{
    // LDS 60928 B -> 2 blocks/CU
    // [0,25088)      sFC  [32][392] bf16   (after B2; aliases leaf-X rows 0..91)
    // [0,34816)      sXb  [128][136] bf16  (P0..P1p; leaves 0..95 = 3t+pos, parents 96+t)
    // [26112,34816)  sAux [32][136] bf16   (after B1.5: FPRE; after B3: parent h)
    // [34816,60928)  sH   [96][136] bf16   (leaf h)
    __shared__ char lds[60928];
    unsigned short* sXb  = (unsigned short*)lds;
    unsigned short* sFC  = (unsigned short*)lds;
    unsigned short* sAux = (unsigned short*)(lds + 26112);
    unsigned short* sH   = (unsigned short*)(lds + 34816);

    const int tid  = threadIdx.x;
    const int w    = tid >> 6;
    const int lane = tid & 63;
    const int l15  = lane & 15;
    const int l4   = lane >> 4;
    const int jj   = w * 16 + l15;             // wave's output column (0..127 per gate)
    const size_t baseN = (size_t)blockIdx.x * (NTT*4);

    // ---- W-stationary B-fragments + biases ----
    bf16x8 Bw[3][4];
    #pragma unroll
    for (int g = 0; g < 3; ++g)
        #pragma unroll
        for (int ks = 0; ks < 4; ++ks)
            Bw[g][ks] = *(const bf16x8*)(Wiou + (size_t)(g*FDIM + jj)*FDIM + ks*32 + l4*8);
    const float bi = b_iou[jj], bo = b_iou[FDIM + jj], bu = b_iou[2*FDIM + jj];
    const float bfv = b_f[jj],  bc = b_c[jj];

    // ---- P0: load X (128 rows), permute rows, convert bf16 ----
    {
        const f32x4* gx = (const f32x4*)(X + baseN * FDIM);
        #pragma unroll
        for (int it = 0; it < 8; ++it){
            int idx  = tid + it * 512;          // 0..4095 float4s
            int nrow = idx >> 5;                // node 0..127
            int c4   = (idx & 31) << 2;
            int t = nrow >> 2, pos = nrow & 3;
            int srow = (pos < 3) ? (t*3 + pos) : (96 + t);
            f32x4 v = gx[idx];
            ushort4 b;
            b.x = f2bf(v[0]); b.y = f2bf(v[1]); b.z = f2bf(v[2]); b.w = f2bf(v[3]);
            *(ushort4*)&sXb[srow * RS + c4] = b;
        }
    }
    __syncthreads();                           // B1

    // ---- P1: 6 leaf tiles; c -> f32 registers, h -> sH (bf16) ----
    float cvreg[6][4];
    #pragma unroll
    for (int mt = 0; mt < 6; ++mt){
        f32x4 aI = {0.f,0.f,0.f,0.f}, aO = {0.f,0.f,0.f,0.f}, aU = {0.f,0.f,0.f,0.f};
        #pragma unroll
        for (int ks = 0; ks < 4; ++ks){
            bf16x8 A = *(const bf16x8*)&sXb[(mt*16 + l15)*RS + ks*32 + l4*8];
            aI = __builtin_amdgcn_mfma_f32_16x16x32_bf16(A, Bw[0][ks], aI, 0,0,0);
            aO = __builtin_amdgcn_mfma_f32_16x16x32_bf16(A, Bw[1][ks], aO, 0,0,0);
            aU = __builtin_amdgcn_mfma_f32_16x16x32_bf16(A, Bw[2][ks], aU, 0,0,0);
        }
        #pragma unroll
        for (int r = 0; r < 4; ++r){
            int li = mt*16 + l4*4 + r;         // leaf 0..95
            float cv = sigf(aI[r]+bi) * tanh_(aU[r]+bu);
            float hv = sigf(aO[r]+bo) * tanh_(cv);
            cvreg[mt][r] = cv;
            sH[li*RS + jj] = f2bf(hv);
        }
    }

    // ---- P1p: 2 parent tiles; IOU preacts + fp -> registers ----
    f32x4 pI[2], pO[2], pU[2], fp[2];
    #pragma unroll
    for (int pt = 0; pt < 2; ++pt){
        pI[pt] = (f32x4){0.f,0.f,0.f,0.f}; pO[pt] = (f32x4){0.f,0.f,0.f,0.f};
        pU[pt] = (f32x4){0.f,0.f,0.f,0.f}; fp[pt] = (f32x4){0.f,0.f,0.f,0.f};
        #pragma unroll
        for (int ks = 0; ks < 4; ++ks){
            bf16x8 A  = *(const bf16x8*)&sXb[(96 + pt*16 + l15)*RS + ks*32 + l4*8];
            bf16x8 Bf = *(const bf16x8*)(Wf + (size_t)jj*FDIM + ks*32 + l4*8);
            pI[pt] = __builtin_amdgcn_mfma_f32_16x16x32_bf16(A, Bw[0][ks], pI[pt], 0,0,0);
            pO[pt] = __builtin_amdgcn_mfma_f32_16x16x32_bf16(A, Bw[1][ks], pO[pt], 0,0,0);
            pU[pt] = __builtin_amdgcn_mfma_f32_16x16x32_bf16(A, Bw[2][ks], pU[pt], 0,0,0);
            fp[pt] = __builtin_amdgcn_mfma_f32_16x16x32_bf16(A, Bf[0]*0 + Bf, fp[pt], 0,0,0);
        }
    }
    __syncthreads();                           // B1.5: ALL X reads done -> parent-X region reusable

    // ---- FPRE (bf16) -> sAux (overwrites dead parent-X rows) ----
    #pragma unroll
    for (int pt = 0; pt < 2; ++pt)
        #pragma unroll
        for (int r = 0; r < 4; ++r)
            sAux[(pt*16 + l4*4 + r)*RS + jj] = f2bf(fp[pt][r] + bfv);

    // issue Uf B-frags before the barrier
    bf16x8 Bu[4];
    #pragma unroll
    for (int ks = 0; ks < 4; ++ks)
        Bu[ks] = *(const bf16x8*)(Uf + (size_t)jj*FDIM + ks*32 + l4*8);

    __syncthreads();                           // B2: FPRE visible; leaf-X dead -> sFC writable

    // ---- P3: f = sig(FPRE + Uf@h_child); fc = f * c(reg) -> sFC bf16 ----
    #pragma unroll
    for (int mt = 0; mt < 6; ++mt){
        f32x4 acc = {0.f,0.f,0.f,0.f};
        #pragma unroll
        for (int ks = 0; ks < 4; ++ks){
            bf16x8 A = *(const bf16x8*)&sH[(mt*16 + l15)*RS + ks*32 + l4*8];
            acc = __builtin_amdgcn_mfma_f32_16x16x32_bf16(A, Bu[ks], acc, 0,0,0);
        }
        #pragma unroll
        for (int r = 0; r < 4; ++r){
            int li = mt*16 + l4*4 + r;
            int t = li / 3, el = li - 3*t;
            float f  = sigf(acc[r] + bf2f(sAux[t*RS + jj]));
            float fc = f * cvreg[mt][r];
            sFC[t*FCRS + el*FDIM + jj] = f2bf(fc);
        }
    }

    // ---- P2: pIOU += Uiou @ concat(h_children); B-frags shared across 2 M-tiles ----
    {
        bf16x8 Up[2][3];
        #pragma unroll
        for (int p = 0; p < 2; ++p)
            #pragma unroll
            for (int g = 0; g < 3; ++g)
                Up[p][g] = *(const bf16x8*)(Uiou + (size_t)(g*FDIM + jj)*384 + p*32 + l4*8);
        #pragma unroll
        for (int ks = 0; ks < 12; ++ks){
            bf16x8 A0 = *(const bf16x8*)&sH[(3*l15        + (ks>>2))*RS + (ks&3)*32 + l4*8];
            bf16x8 A1 = *(const bf16x8*)&sH[(3*(16 + l15) + (ks>>2))*RS + (ks&3)*32 + l4*8];
            bf16x8 b0 = Up[ks&1][0], b1 = Up[ks&1][1], b2 = Up[ks&1][2];
            if (ks < 10){
                #pragma unroll
                for (int g = 0; g < 3; ++g)
                    Up[ks&1][g] = *(const bf16x8*)(Uiou + (size_t)(g*FDIM + jj)*384 + (ks+2)*32 + l4*8);
            }
            pI[0] = __builtin_amdgcn_mfma_f32_16x16x32_bf16(A0, b0, pI[0], 0,0,0);
            pI[1] = __builtin_amdgcn_mfma_f32_16x16x32_bf16(A1, b0, pI[1], 0,0,0);
            pO[0] = __builtin_amdgcn_mfma_f32_16x16x32_bf16(A0, b1, pO[0], 0,0,0);
            pO[1] = __builtin_amdgcn_mfma_f32_16x16x32_bf16(A1, b1, pO[1], 0,0,0);
            pU[0] = __builtin_amdgcn_mfma_f32_16x16x32_bf16(A0, b2, pU[0], 0,0,0);
            pU[1] = __builtin_amdgcn_mfma_f32_16x16x32_bf16(A1, b2, pU[1], 0,0,0);
        }
    }
    __syncthreads();                           // B3: sFC complete; FPRE reads done

    // ---- P4: c_p = i*u + Wc@fc + b_c ; h_p (bf16) -> sAux ----
    {
        f32x4 aC0 = {0.f,0.f,0.f,0.f}, aC1 = {0.f,0.f,0.f,0.f};
        #pragma unroll
        for (int ks = 0; ks < 12; ++ks){
            bf16x8 B  = *(const bf16x8*)(Wc + (size_t)jj*384 + ks*32 + l4*8);
            bf16x8 A0 = *(const bf16x8*)&sFC[(l15     )*FCRS + ks*32 + l4*8];
            bf16x8 A1 = *(const bf16x8*)&sFC[(16 + l15)*FCRS + ks*32 + l4*8];
            aC0 = __builtin_amdgcn_mfma_f32_16x16x32_bf16(A0, B, aC0, 0,0,0);
            aC1 = __builtin_amdgcn_mfma_f32_16x16x32_bf16(A1, B, aC1, 0,0,0);
        }
        #pragma unroll
        for (int pt = 0; pt < 2; ++pt){
            f32x4 aC = pt ? aC1 : aC0;
            #pragma unroll
            for (int r = 0; r < 4; ++r){
                float cp = sigf(pI[pt][r]+bi) * tanh_(pU[pt][r]+bu) + aC[r] + bc;
                float hp = sigf(pO[pt][r]+bo) * tanh_(cp);
                sAux[(pt*16 + l4*4 + r)*RS + jj] = f2bf(hp);
            }
        }
    }
    __syncthreads();                           // B4: sH + sAux fully populated

    // ---- final dump: bf16 -> f32, full-line coalesced stores ----
    {
        float* go = Hout + baseN * FDIM;
        #pragma unroll
        for (int it = 0; it < 8; ++it){
            int idx  = tid + it * 512;          // 0..4095
            int nrow = idx >> 5;                // node 0..127 (global order)
            int c4   = (idx & 31) << 2;
            int t = nrow >> 2, pos = nrow & 3;
            ushort4 hb = (pos < 3) ? *(const ushort4*)&sH[(t*3 + pos)*RS + c4]
                                   : *(const ushort4*)&sAux[t*RS + c4];
            f32x4 v;
            v[0] = bf2f(hb.x); v[1] = bf2f(hb.y); v[2] = bf2f(hb.z); v[3] = bf2f(hb.w);
            *(f32x4*)(go + nrow*FDIM + c4) = v;
        }
    }
}

extern "C" void kernel_launch(void* const* d_in, const int* in_sizes, int n_in,
                              void* d_out, int out_size, void* d_ws, size_t ws_size,
                              hipStream_t stream)
{
    const float* forest = (const float*)d_in[0];
    const float* W_iou  = (const float*)d_in[4];
    const float* b_iou  = (const float*)d_in[5];
    const float* U_iou  = (const float*)d_in[6];
    const float* W_c    = (const float*)d_in[7];
    const float* b_c    = (const float*)d_in[8];
    const float* W_f    = (const float*)d_in[9];
    const float* b_f    = (const float*)d_in[10];
    const float* U_f    = (const float*)d_in[11];
    float* Hout = (float*)d_out;

    unsigned short* wsb = (unsigned short*)d_ws;
    unsigned short* bWiou = wsb;                // 49152 elems
    unsigned short* bUiou = wsb + 49152;        // 147456
    unsigned short* bWc   = wsb + 196608;       // 49152
    unsigned short* bWf   = wsb + 245760;       // 16384
    unsigned short* bUf   = wsb + 262144;       // 16384

    hipLaunchKernelGGL(cvt_all, dim3(272), dim3(256), 0, stream,
                       W_iou, U_iou, W_c, W_f, U_f, wsb);

    const int trees = in_sizes[0] / (4 * FDIM); // 65536
    const int grid  = trees / NTT;              // 2048

    hipLaunchKernelGGL(treelstm_mfma, dim3(grid), dim3(512), 0, stream,
                       forest, bWiou, bUiou, bWc, bWf, bUf, b_iou, b_c, b_f, Hout);
}

// Round 9
// 260.128 us; speedup vs baseline: 2.2414x; 1.0258x over previous
//
#include <hip/hip_runtime.h>

#define FDIM  128
#define NTT   32          // trees per block
#define RS    136         // bf16 row stride for sXb/sH/sAux
#define FCRS  392         // bf16 row stride for sFC

typedef __attribute__((ext_vector_type(8))) short bf16x8;
typedef __attribute__((ext_vector_type(4))) float f32x4;

__device__ __forceinline__ unsigned short f2bf(float f){
    unsigned u = __builtin_bit_cast(unsigned, f);
    u += 0x7fffu + ((u >> 16) & 1u);          // RNE
    return (unsigned short)(u >> 16);
}
__device__ __forceinline__ float bf2f(unsigned short b){
    unsigned u = ((unsigned)b) << 16;
    return __builtin_bit_cast(float, u);
}
__device__ __forceinline__ float sigf(float x){ return 1.0f/(1.0f+__expf(-x)); }
__device__ __forceinline__ float tanh_(float x){ return 1.0f - 2.0f/(__expf(2.0f*x)+1.0f); }

// ---- fused fp32 -> bf16 conversion of all 5 weight matrices (1 launch) ----
__global__ void cvt_all(const float* __restrict__ W_iou, const float* __restrict__ U_iou,
                        const float* __restrict__ W_c,   const float* __restrict__ W_f,
                        const float* __restrict__ U_f,   unsigned short* __restrict__ dst)
{
    int i = blockIdx.x * 256 + threadIdx.x;      // float4 index, 0..69631
    const float* src; int base;
    if      (i < 12288){ src = W_iou; base = 0; }
    else if (i < 49152){ src = U_iou; base = 12288; }
    else if (i < 61440){ src = W_c;   base = 49152; }
    else if (i < 65536){ src = W_f;   base = 61440; }
    else               { src = U_f;   base = 65536; }
    float4 v = ((const float4*)src)[i - base];
    ushort4 b;
    b.x = f2bf(v.x); b.y = f2bf(v.y); b.z = f2bf(v.z); b.w = f2bf(v.w);
    ((ushort4*)dst)[i] = b;
}

__global__ __launch_bounds__(512)
__attribute__((amdgpu_waves_per_eu(4, 4)))        // LDS caps us at 2 blocks/CU = 4 waves/EU;
void treelstm_mfma(                               // let the allocator use the full 128 VGPRs
    const float* __restrict__ X,
    const unsigned short* __restrict__ Wiou,   // [384][128] bf16
    const unsigned short* __restrict__ Uiou,   // [384][384] bf16
    const unsigned short* __restrict__ Wc,     // [128][384] bf16
    const unsigned short* __restrict__ Wf,     // [128][128] bf16
    const unsigned short* __restrict__ Uf,     // [128][128] bf16
    const float* __restrict__ b_iou,
    const float* __restrict__ b_c,
    const float* __restrict__ b_f,
    float* __restrict__ Hout)
{
    // LDS 60928 B -> 2 blocks/CU
    // [0,25088)      sFC  [32][392] bf16   (after B1.5; aliases dead leaf-X rows)
    // [0,34816)      sXb  [128][136] bf16  (P0..P1p; leaves 0..95 = 3t+pos, parents 96+t)
    // [26112,34816)  sAux [32][136] bf16   (after B1.5: FPRE; after B3: parent h)
    // [34816,60928)  sH   [96][136] bf16   (leaf h)
    __shared__ char lds[60928];
    unsigned short* sXb  = (unsigned short*)lds;
    unsigned short* sFC  = (unsigned short*)lds;
    unsigned short* sAux = (unsigned short*)(lds + 26112);
    unsigned short* sH   = (unsigned short*)(lds + 34816);

    const int tid  = threadIdx.x;
    const int w    = tid >> 6;
    const int lane = tid & 63;
    const int l15  = lane & 15;
    const int l4   = lane >> 4;
    const int jj   = w * 16 + l15;             // wave's output column (0..127 per gate)
    const size_t baseN = (size_t)blockIdx.x * (NTT*4);

    // ---- W-stationary B-fragments + biases ----
    bf16x8 Bw[3][4];
    #pragma unroll
    for (int g = 0; g < 3; ++g)
        #pragma unroll
        for (int ks = 0; ks < 4; ++ks)
            Bw[g][ks] = *(const bf16x8*)(Wiou + (size_t)(g*FDIM + jj)*FDIM + ks*32 + l4*8);
    bf16x8 Bfr[4];
    #pragma unroll
    for (int ks = 0; ks < 4; ++ks)
        Bfr[ks] = *(const bf16x8*)(Wf + (size_t)jj*FDIM + ks*32 + l4*8);
    const float bi = b_iou[jj], bo = b_iou[FDIM + jj], bu = b_iou[2*FDIM + jj];
    const float bfv = b_f[jj],  bc = b_c[jj];

    // ---- P0: load X (128 rows), permute rows, convert bf16 ----
    {
        const f32x4* gx = (const f32x4*)(X + baseN * FDIM);
        #pragma unroll
        for (int it = 0; it < 8; ++it){
            int idx  = tid + it * 512;          // 0..4095 float4s
            int nrow = idx >> 5;                // node 0..127
            int c4   = (idx & 31) << 2;
            int t = nrow >> 2, pos = nrow & 3;
            int srow = (pos < 3) ? (t*3 + pos) : (96 + t);
            f32x4 v = gx[idx];
            ushort4 b;
            b.x = f2bf(v[0]); b.y = f2bf(v[1]); b.z = f2bf(v[2]); b.w = f2bf(v[3]);
            *(ushort4*)&sXb[srow * RS + c4] = b;
        }
    }
    __syncthreads();                           // B1

    // ---- P1: 6 leaf tiles; c -> PACKED bf16 registers, h -> sH (bf16) ----
    unsigned cpack[6][2];                      // [mt][rpair]: 2x bf16 per u32
    #pragma unroll
    for (int mt = 0; mt < 6; ++mt){
        f32x4 aI = {0.f,0.f,0.f,0.f}, aO = {0.f,0.f,0.f,0.f}, aU = {0.f,0.f,0.f,0.f};
        #pragma unroll
        for (int ks = 0; ks < 4; ++ks){
            bf16x8 A = *(const bf16x8*)&sXb[(mt*16 + l15)*RS + ks*32 + l4*8];
            aI = __builtin_amdgcn_mfma_f32_16x16x32_bf16(A, Bw[0][ks], aI, 0,0,0);
            aO = __builtin_amdgcn_mfma_f32_16x16x32_bf16(A, Bw[1][ks], aO, 0,0,0);
            aU = __builtin_amdgcn_mfma_f32_16x16x32_bf16(A, Bw[2][ks], aU, 0,0,0);
        }
        #pragma unroll
        for (int rp = 0; rp < 2; ++rp){
            unsigned pk = 0;
            #pragma unroll
            for (int q = 0; q < 2; ++q){
                int r = rp*2 + q;
                int li = mt*16 + l4*4 + r;     // leaf 0..95
                float cv = sigf(aI[r]+bi) * tanh_(aU[r]+bu);
                float hv = sigf(aO[r]+bo) * tanh_(cv);
                pk |= ((unsigned)f2bf(cv)) << (16*q);
                sH[li*RS + jj] = f2bf(hv);
            }
            cpack[mt][rp] = pk;
        }
    }

    // ---- P1p: 2 parent tiles; IOU preacts + fp -> registers ----
    f32x4 pI[2], pO[2], pU[2], fp[2];
    #pragma unroll
    for (int pt = 0; pt < 2; ++pt){
        pI[pt] = (f32x4){0.f,0.f,0.f,0.f}; pO[pt] = (f32x4){0.f,0.f,0.f,0.f};
        pU[pt] = (f32x4){0.f,0.f,0.f,0.f}; fp[pt] = (f32x4){0.f,0.f,0.f,0.f};
        #pragma unroll
        for (int ks = 0; ks < 4; ++ks){
            bf16x8 A = *(const bf16x8*)&sXb[(96 + pt*16 + l15)*RS + ks*32 + l4*8];
            pI[pt] = __builtin_amdgcn_mfma_f32_16x16x32_bf16(A, Bw[0][ks], pI[pt], 0,0,0);
            pO[pt] = __builtin_amdgcn_mfma_f32_16x16x32_bf16(A, Bw[1][ks], pO[pt], 0,0,0);
            pU[pt] = __builtin_amdgcn_mfma_f32_16x16x32_bf16(A, Bw[2][ks], pU[pt], 0,0,0);
            fp[pt] = __builtin_amdgcn_mfma_f32_16x16x32_bf16(A, Bfr[ks], fp[pt], 0,0,0);
        }
    }
    __syncthreads();                           // B1.5: X fully consumed; sH visible

    // ---- FPRE (bf16) -> sAux (overwrites dead parent-X rows) ----
    #pragma unroll
    for (int pt = 0; pt < 2; ++pt)
        #pragma unroll
        for (int r = 0; r < 4; ++r)
            sAux[(pt*16 + l4*4 + r)*RS + jj] = f2bf(fp[pt][r] + bfv);

    // issue Uf B-frags now; consumed in P3 after P2 (long latency cover)
    bf16x8 Bu[4];
    #pragma unroll
    for (int ks = 0; ks < 4; ++ks)
        Bu[ks] = *(const bf16x8*)(Uf + (size_t)jj*FDIM + ks*32 + l4*8);

    // ---- P2: pIOU += Uiou @ concat(h_children); 2-deep Uiou prefetch ----
    {
        bf16x8 Up[2][3];
        #pragma unroll
        for (int p = 0; p < 2; ++p)
            #pragma unroll
            for (int g = 0; g < 3; ++g)
                Up[p][g] = *(const bf16x8*)(Uiou + (size_t)(g*FDIM + jj)*384 + p*32 + l4*8);
        #pragma unroll
        for (int ks = 0; ks < 12; ++ks){
            bf16x8 A0 = *(const bf16x8*)&sH[(3*l15        + (ks>>2))*RS + (ks&3)*32 + l4*8];
            bf16x8 A1 = *(const bf16x8*)&sH[(3*(16 + l15) + (ks>>2))*RS + (ks&3)*32 + l4*8];
            bf16x8 b0 = Up[ks&1][0], b1 = Up[ks&1][1], b2 = Up[ks&1][2];
            if (ks < 10){
                #pragma unroll
                for (int g = 0; g < 3; ++g)
                    Up[ks&1][g] = *(const bf16x8*)(Uiou + (size_t)(g*FDIM + jj)*384 + (ks+2)*32 + l4*8);
            }
            pI[0] = __builtin_amdgcn_mfma_f32_16x16x32_bf16(A0, b0, pI[0], 0,0,0);
            pI[1] = __builtin_amdgcn_mfma_f32_16x16x32_bf16(A1, b0, pI[1], 0,0,0);
            pO[0] = __builtin_amdgcn_mfma_f32_16x16x32_bf16(A0, b1, pO[0], 0,0,0);
            pO[1] = __builtin_amdgcn_mfma_f32_16x16x32_bf16(A1, b1, pO[1], 0,0,0);
            pU[0] = __builtin_amdgcn_mfma_f32_16x16x32_bf16(A0, b2, pU[0], 0,0,0);
            pU[1] = __builtin_amdgcn_mfma_f32_16x16x32_bf16(A1, b2, pU[1], 0,0,0);
        }
    }

    // ---- fold parent gates now: frees pI/pO/pU (24 regs) -> iu/o (16 regs) ----
    f32x4 giu[2], go[2];
    #pragma unroll
    for (int pt = 0; pt < 2; ++pt)
        #pragma unroll
        for (int r = 0; r < 4; ++r){
            giu[pt][r] = sigf(pI[pt][r]+bi) * tanh_(pU[pt][r]+bu);
            go[pt][r]  = sigf(pO[pt][r]+bo);
        }

    // ---- P3: f = sig(FPRE + Uf@h_child); fc = f * c(packed reg) -> sFC bf16 ----
    #pragma unroll
    for (int mt = 0; mt < 6; ++mt){
        f32x4 acc = {0.f,0.f,0.f,0.f};
        #pragma unroll
        for (int ks = 0; ks < 4; ++ks){
            bf16x8 A = *(const bf16x8*)&sH[(mt*16 + l15)*RS + ks*32 + l4*8];
            acc = __builtin_amdgcn_mfma_f32_16x16x32_bf16(A, Bu[ks], acc, 0,0,0);
        }
        #pragma unroll
        for (int r = 0; r < 4; ++r){
            int li = mt*16 + l4*4 + r;
            int t = li / 3, el = li - 3*t;
            float f  = sigf(acc[r] + bf2f(sAux[t*RS + jj]));
            float cv = bf2f((unsigned short)((cpack[mt][r>>1] >> (16*(r&1))) & 0xffffu));
            sFC[t*FCRS + el*FDIM + jj] = f2bf(f * cv);
        }
    }
    __syncthreads();                           // B3: sFC complete; sAux(FPRE) reads done

    // ---- P4: c_p = i*u + Wc@fc + b_c ; h_p (bf16) -> sAux ----
    {
        f32x4 aC0 = {0.f,0.f,0.f,0.f}, aC1 = {0.f,0.f,0.f,0.f};
        #pragma unroll
        for (int ks = 0; ks < 12; ++ks){
            bf16x8 B  = *(const bf16x8*)(Wc + (size_t)jj*384 + ks*32 + l4*8);
            bf16x8 A0 = *(const bf16x8*)&sFC[(l15     )*FCRS + ks*32 + l4*8];
            bf16x8 A1 = *(const bf16x8*)&sFC[(16 + l15)*FCRS + ks*32 + l4*8];
            aC0 = __builtin_amdgcn_mfma_f32_16x16x32_bf16(A0, B, aC0, 0,0,0);
            aC1 = __builtin_amdgcn_mfma_f32_16x16x32_bf16(A1, B, aC1, 0,0,0);
        }
        #pragma unroll
        for (int pt = 0; pt < 2; ++pt){
            f32x4 aC = pt ? aC1 : aC0;
            #pragma unroll
            for (int r = 0; r < 4; ++r){
                float cp = giu[pt][r] + aC[r] + bc;
                float hp = go[pt][r] * tanh_(cp);
                sAux[(pt*16 + l4*4 + r)*RS + jj] = f2bf(hp);
            }
        }
    }
    __syncthreads();                           // B4: sH + sAux fully populated

    // ---- final dump: bf16 -> f32, full-line coalesced stores ----
    {
        float* go_ = Hout + baseN * FDIM;
        #pragma unroll
        for (int it = 0; it < 8; ++it){
            int idx  = tid + it * 512;          // 0..4095
            int nrow = idx >> 5;                // node 0..127 (global order)
            int c4   = (idx & 31) << 2;
            int t = nrow >> 2, pos = nrow & 3;
            ushort4 hb = (pos < 3) ? *(const ushort4*)&sH[(t*3 + pos)*RS + c4]
                                   : *(const ushort4*)&sAux[t*RS + c4];
            f32x4 v;
            v[0] = bf2f(hb.x); v[1] = bf2f(hb.y); v[2] = bf2f(hb.z); v[3] = bf2f(hb.w);
            *(f32x4*)(go_ + nrow*FDIM + c4) = v;
        }
    }
}

extern "C" void kernel_launch(void* const* d_in, const int* in_sizes, int n_in,
                              void* d_out, int out_size, void* d_ws, size_t ws_size,
                              hipStream_t stream)
{
    const float* forest = (const float*)d_in[0];
    const float* W_iou  = (const float*)d_in[4];
    const float* b_iou  = (const float*)d_in[5];
    const float* U_iou  = (const float*)d_in[6];
    const float* W_c    = (const float*)d_in[7];
    const float* b_c    = (const float*)d_in[8];
    const float* W_f    = (const float*)d_in[9];
    const float* b_f    = (const float*)d_in[10];
    const float* U_f    = (const float*)d_in[11];
    float* Hout = (float*)d_out;

    unsigned short* wsb = (unsigned short*)d_ws;
    unsigned short* bWiou = wsb;                // 49152 elems
    unsigned short* bUiou = wsb + 49152;        // 147456
    unsigned short* bWc   = wsb + 196608;       // 49152
    unsigned short* bWf   = wsb + 245760;       // 16384
    unsigned short* bUf   = wsb + 262144;       // 16384

    hipLaunchKernelGGL(cvt_all, dim3(272), dim3(256), 0, stream,
                       W_iou, U_iou, W_c, W_f, U_f, wsb);

    const int trees = in_sizes[0] / (4 * FDIM); // 65536
    const int grid  = trees / NTT;              // 2048

    hipLaunchKernelGGL(treelstm_mfma, dim3(grid), dim3(512), 0, stream,
                       forest, bWiou, bUiou, bWc, bWf, bUf, b_iou, b_c, b_f, Hout);
}